// Round 2
// baseline (2097.264 us; speedup 1.0000x reference)
//
#include <hip/hip_runtime.h>
#include <stdint.h>

// ---------- types / helpers ----------
typedef short     bf16x8  __attribute__((ext_vector_type(8)));
typedef float     f32x4   __attribute__((ext_vector_type(4)));
typedef unsigned short ushort8 __attribute__((ext_vector_type(8)));

__device__ __forceinline__ float bf2f(unsigned short u) {
    union { unsigned int i; float f; } v; v.i = ((unsigned int)u) << 16; return v.f;
}
__device__ __forceinline__ unsigned short f2bf(float f) {
    union { float f; unsigned int i; } v; v.f = f;
    unsigned int x = v.i;
    return (unsigned short)((x + 0x7fffu + ((x >> 16) & 1u)) >> 16);
}
__device__ __forceinline__ float ldv(float x) { return x; }
__device__ __forceinline__ float ldv(unsigned short u) { return bf2f(u); }

// ---------- conv + BN (eval), stride2 pad1, 3x3; fp32 weights, bf16 out ----------
template <typename Tin>
__global__ void conv_bn_kernel(const Tin* __restrict__ in,
                               const float* __restrict__ w,
                               const float* __restrict__ bias,
                               const float* __restrict__ bng,
                               const float* __restrict__ bnb,
                               unsigned short* __restrict__ out,
                               int B, int Cin, int H, int W_, int Cout)
{
    int OH = H >> 1, OW = W_ >> 1;
    int total = B * Cout * OH * OW;
    int idx = blockIdx.x * blockDim.x + threadIdx.x;
    if (idx >= total) return;
    int ow = idx % OW; int tmp = idx / OW;
    int oh = tmp % OH; tmp /= OH;
    int co = tmp % Cout; int b = tmp / Cout;

    float acc = 0.f;
    int ih0 = 2 * oh - 1, iw0 = 2 * ow - 1;
    const float* wp = w + co * Cin * 9;
    const Tin* ip = in + (size_t)b * Cin * H * W_;
    for (int ci = 0; ci < Cin; ++ci) {
        const Tin* ipc = ip + ci * H * W_;
        const float* wpc = wp + ci * 9;
        #pragma unroll
        for (int ky = 0; ky < 3; ++ky) {
            int ih = ih0 + ky;
            if (ih < 0) continue;              // ih < H always holds (stride2, pad1)
            const Tin* iprow = ipc + ih * W_;
            #pragma unroll
            for (int kx = 0; kx < 3; ++kx) {
                int iw = iw0 + kx;
                if (iw < 0) continue;          // iw < W always holds
                acc += ldv(iprow[iw]) * wpc[ky * 3 + kx];
            }
        }
    }
    float scale = bng[co] * 0.9999950000374997f;  // 1/sqrt(1+1e-5)
    float r = (acc + bias[co]) * scale + bnb[co];
    out[idx] = f2bf(r);
}

// ---------- fp32 -> bf16 weight conversion ----------
__global__ void f2bf_kernel(const float* __restrict__ in, unsigned short* __restrict__ out, int n)
{
    int i = blockIdx.x * blockDim.x + threadIdx.x;
    if (i < n) out[i] = f2bf(in[i]);
}

// ---------- g1 decomposition prep ----------
// A[b,o,u]  = sum_c g1_w[u, c]    * x_flat[b,o,c]   (j-side, cols 0..25)
// Bv[b,o,u] = sum_c g1_w[u, 26+c] * x_flat[b,o,c]   (i-side)
__global__ void prep_ab_kernel(const unsigned short* __restrict__ c4,
                               const float* __restrict__ g1w,
                               unsigned short* __restrict__ A, unsigned short* __restrict__ Bv)
{
    int bo = blockIdx.x;            // b*25 + o
    int o = bo % 25, b = bo / 25;
    __shared__ float xf[26];
    int t = threadIdx.x;
    if (t < 24)       xf[t]  = bf2f(c4[((size_t)b * 24 + t) * 25 + o]);
    else if (t == 24) xf[24] = ((o / 5) - 2) * 0.5f;
    else if (t == 25) xf[25] = ((o % 5) - 2) * 0.5f;
    __syncthreads();
    float a = 0.f, bb = 0.f;
    #pragma unroll
    for (int c = 0; c < 26; ++c) {
        float x = xf[c];
        a  += g1w[t * 63 + c] * x;
        bb += g1w[t * 63 + 26 + c] * x;
    }
    A [(size_t)bo * 256 + t] = f2bf(a);
    Bv[(size_t)bo * 256 + t] = f2bf(bb);
}

// Cq[b,u] = sum_k g1_w[u,52+k]*q[b,k] + g1_b[u]
__global__ void prep_c_kernel(const float* __restrict__ q,
                              const float* __restrict__ g1w,
                              const float* __restrict__ g1b,
                              float* __restrict__ Cq)
{
    int b = blockIdx.x, u = threadIdx.x;
    float acc = g1b[u];
    #pragma unroll
    for (int k = 0; k < 11; ++k)
        acc += g1w[u * 63 + 52 + k] * q[b * 11 + k];
    Cq[(size_t)b * 256 + u] = acc;
}

__global__ void zero_kernel(float* __restrict__ p, int n)
{
    int i = blockIdx.x * blockDim.x + threadIdx.x;
    if (i < n) p[i] = 0.f;
}

// ---------- fused g2/g3/g4 + pair-sum ----------
// Grid: 512*5 WGs; WG = (b, tile of 128 pair-rows of 625 padded to 640).
// 8 waves: wave = 64 rows x 64 cols of the 128x256 tile.
// LDS: X,Y ping-pong 128x256 bf16 each, XOR-swizzled in 16B granules (static 128KB).
__global__ __launch_bounds__(512, 2) void gmlp_kernel(
    const unsigned short* __restrict__ A, const unsigned short* __restrict__ Bv,
    const float* __restrict__ Cq,
    const unsigned short* __restrict__ w2, const float* __restrict__ b2,
    const unsigned short* __restrict__ w3, const float* __restrict__ b3,
    const unsigned short* __restrict__ w4, const float* __restrict__ b4,
    float* __restrict__ xg)
{
    __shared__ unsigned short smem[2 * 128 * 256];   // 128 KB
    unsigned short* X = smem;
    unsigned short* Y = smem + 128 * 256;

    int blk  = blockIdx.x;
    int b    = blk / 5;
    int tile = blk % 5;
    int row0 = tile * 128;
    int t = threadIdx.x;

    // ---- build h1 = relu(A[b,j] + Bv[b,i] + Cq[b]) into X ----
    {
        int r = t >> 2;           // 0..127
        int quad = t & 3;
        int prow = row0 + r;
        if (prow < 625) {
            int i = prow / 25, j = prow % 25;
            const unsigned short* Ap = A  + ((size_t)b * 25 + j) * 256;
            const unsigned short* Bp = Bv + ((size_t)b * 25 + i) * 256;
            const float* Cp = Cq + (size_t)b * 256;
            #pragma unroll
            for (int k = 0; k < 8; ++k) {
                int g = quad + 4 * k;
                int c0 = g * 8;
                ushort8 av = *(const ushort8*)(Ap + c0);
                ushort8 bv = *(const ushort8*)(Bp + c0);
                f32x4 q0 = *(const f32x4*)(Cp + c0);
                f32x4 q1 = *(const f32x4*)(Cp + c0 + 4);
                ushort8 o;
                #pragma unroll
                for (int e = 0; e < 4; ++e) {
                    o[e]     = f2bf(fmaxf(bf2f(av[e])     + bf2f(bv[e])     + q0[e], 0.f));
                    o[4 + e] = f2bf(fmaxf(bf2f(av[4 + e]) + bf2f(bv[4 + e]) + q1[e], 0.f));
                }
                int sg = g ^ (r & 7);
                *(ushort8*)(X + r * 256 + sg * 8) = o;
            }
        } else {
            ushort8 z = {0,0,0,0,0,0,0,0};
            #pragma unroll
            for (int k = 0; k < 8; ++k) {
                int g = quad + 4 * k;
                int sg = g ^ (r & 7);
                *(ushort8*)(X + r * 256 + sg * 8) = z;
            }
        }
    }
    __syncthreads();

    int wid = t >> 6, lane = t & 63;
    int wr = (wid & 1) * 64;        // wave row base (0 / 64)
    int wc = (wid >> 1) * 64;       // wave col base (0/64/128/192)
    int lr = lane & 15, lh = lane >> 4;

    unsigned short* inb  = X;
    unsigned short* outb = Y;
    const unsigned short* Ws[3] = { w2, w3, w4 };
    const float* Bs[3] = { b2, b3, b4 };

    for (int L = 0; L < 3; ++L) {
        const unsigned short* W = Ws[L];
        float bias[4];
        #pragma unroll
        for (int cb = 0; cb < 4; ++cb) bias[cb] = Bs[L][wc + cb * 16 + lr];

        f32x4 acc[4][4];
        #pragma unroll
        for (int rb = 0; rb < 4; ++rb)
            #pragma unroll
            for (int cb = 0; cb < 4; ++cb)
                acc[rb][cb] = (f32x4){0.f, 0.f, 0.f, 0.f};

        for (int kk = 0; kk < 8; ++kk) {
            int k0 = kk * 32;
            bf16x8 af[4], bfr[4];
            #pragma unroll
            for (int rb = 0; rb < 4; ++rb) {
                int row = wr + rb * 16 + lr;
                int sg = (kk * 4 + lh) ^ (row & 7);
                af[rb] = *(const bf16x8*)(inb + row * 256 + sg * 8);
            }
            #pragma unroll
            for (int cb = 0; cb < 4; ++cb) {
                int u = wc + cb * 16 + lr;
                bfr[cb] = *(const bf16x8*)(W + u * 256 + k0 + lh * 8);
            }
            #pragma unroll
            for (int rb = 0; rb < 4; ++rb)
                #pragma unroll
                for (int cb = 0; cb < 4; ++cb)
                    acc[rb][cb] = __builtin_amdgcn_mfma_f32_16x16x32_bf16(
                        af[rb], bfr[cb], acc[rb][cb], 0, 0, 0);
        }

        if (L < 2) {
            #pragma unroll
            for (int rb = 0; rb < 4; ++rb) {
                #pragma unroll
                for (int cb = 0; cb < 4; ++cb) {
                    #pragma unroll
                    for (int reg = 0; reg < 4; ++reg) {
                        float v = fmaxf(acc[rb][cb][reg] + bias[cb], 0.f);
                        int row = wr + rb * 16 + lh * 4 + reg;
                        int col = wc + cb * 16 + lr;
                        int sg = (col >> 3) ^ (row & 7);
                        outb[row * 256 + sg * 8 + (col & 7)] = f2bf(v);
                    }
                }
            }
            __syncthreads();
            unsigned short* tmp = inb; inb = outb; outb = tmp;
        } else {
            // g4: relu + masked pair-sum, atomically into xg[b]
            float csum[4] = {0.f, 0.f, 0.f, 0.f};
            #pragma unroll
            for (int rb = 0; rb < 4; ++rb) {
                #pragma unroll
                for (int reg = 0; reg < 4; ++reg) {
                    int rowloc = wr + rb * 16 + lh * 4 + reg;
                    bool valid = (row0 + rowloc) < 625;
                    #pragma unroll
                    for (int cb = 0; cb < 4; ++cb) {
                        float v = fmaxf(acc[rb][cb][reg] + bias[cb], 0.f);
                        if (valid) csum[cb] += v;
                    }
                }
            }
            #pragma unroll
            for (int cb = 0; cb < 4; ++cb) {
                csum[cb] += __shfl_xor(csum[cb], 16);
                csum[cb] += __shfl_xor(csum[cb], 32);
            }
            if (lh == 0) {
                #pragma unroll
                for (int cb = 0; cb < 4; ++cb)
                    atomicAdd(&xg[(size_t)b * 256 + wc + cb * 16 + lr], csum[cb]);
            }
        }
    }
}

// ---------- f layers (fp32) ----------
__global__ void fc256_kernel(const float* __restrict__ in, const float* __restrict__ w,
                             const float* __restrict__ bias, float* __restrict__ out)
{
    __shared__ float xs[256];
    int b = blockIdx.x, u = threadIdx.x;
    xs[u] = in[(size_t)b * 256 + u];
    __syncthreads();
    float acc = bias[u];
    const float* wr = w + u * 256;
    #pragma unroll 8
    for (int c = 0; c < 256; ++c) acc += wr[c] * xs[c];
    out[(size_t)b * 256 + u] = fmaxf(acc, 0.f);
}

__global__ void fc_out_kernel(const float* __restrict__ in, const float* __restrict__ w,
                              const float* __restrict__ bias, float* __restrict__ out)
{
    __shared__ float xs[256];
    int b = blockIdx.x, t = threadIdx.x;
    for (int c = t; c < 256; c += 64) xs[c] = in[(size_t)b * 256 + c];
    __syncthreads();
    if (t < 10) {
        float acc = bias[t];
        const float* wr = w + t * 256;
        for (int c = 0; c < 256; ++c) acc += wr[c] * xs[c];
        out[b * 10 + t] = acc;
    }
}

// ---------- launch ----------
extern "C" void kernel_launch(void* const* d_in, const int* in_sizes, int n_in,
                              void* d_out, int out_size, void* d_ws, size_t ws_size,
                              hipStream_t stream)
{
    const float* im  = (const float*)d_in[0];
    const float* q   = (const float*)d_in[1];
    const float* c1w = (const float*)d_in[2];
    const float* c1b = (const float*)d_in[3];
    const float* n1g = (const float*)d_in[4];
    const float* n1b = (const float*)d_in[5];
    const float* c2w = (const float*)d_in[6];
    const float* c2b = (const float*)d_in[7];
    const float* n2g = (const float*)d_in[8];
    const float* n2b = (const float*)d_in[9];
    const float* c3w = (const float*)d_in[10];
    const float* c3b = (const float*)d_in[11];
    const float* n3g = (const float*)d_in[12];
    const float* n3b = (const float*)d_in[13];
    const float* c4w = (const float*)d_in[14];
    const float* c4b = (const float*)d_in[15];
    const float* n4g = (const float*)d_in[16];
    const float* n4b = (const float*)d_in[17];
    const float* g1w = (const float*)d_in[18];
    const float* g1b = (const float*)d_in[19];
    const float* g2w = (const float*)d_in[20];
    const float* g2b = (const float*)d_in[21];
    const float* g3w = (const float*)d_in[22];
    const float* g3b = (const float*)d_in[23];
    const float* g4w = (const float*)d_in[24];
    const float* g4b = (const float*)d_in[25];
    const float* f1w = (const float*)d_in[26];
    const float* f1b = (const float*)d_in[27];
    const float* f2w = (const float*)d_in[28];
    const float* f2b = (const float*)d_in[29];
    const float* f3w = (const float*)d_in[30];
    const float* f3b = (const float*)d_in[31];

    char* ws = (char*)d_ws;
    size_t off = 0;
    auto alloc = [&](size_t bytes) -> void* {
        void* p = ws + off;
        off += (bytes + 255) & ~(size_t)255;
        return p;
    };
    // bf16 copies of g-MLP weights
    unsigned short* wg2 = (unsigned short*)alloc(65536ull * 2);
    unsigned short* wg3 = (unsigned short*)alloc(65536ull * 2);
    unsigned short* wg4 = (unsigned short*)alloc(65536ull * 2);
    // g1 decomposition (bf16) and small f32 buffers
    unsigned short* A   = (unsigned short*)alloc(3276800ull * 2);   // 512x25x256
    unsigned short* Bv  = (unsigned short*)alloc(3276800ull * 2);
    float* Cq  = (float*)alloc(131072ull * 4);                      // 512x256
    float* xg  = (float*)alloc(131072ull * 4);
    float* t1  = (float*)alloc(131072ull * 4);
    float* t2  = (float*)alloc(131072ull * 4);
    // conv region (aliased): c2o full batch; c1o chunk; then c3o/c4o reuse
    unsigned short* c2o = (unsigned short*)alloc(4915200ull * 2);   // 512x24x20x20
    unsigned short* c1o = (unsigned short*)alloc(4915200ull * 2);   // 128x24x40x40 chunk
    unsigned short* c3o = c1o;   // 512x24x10x10 = 1,228,800 elems (c1o dead)
    unsigned short* c4o = c2o;   // 512x24x5x5   =   307,200 elems (c2o dead)

    // conv1/conv2, chunked by 128 batch to bound scratch
    for (int b0 = 0; b0 < 512; b0 += 128) {
        conv_bn_kernel<float><<<(4915200 + 255) / 256, 256, 0, stream>>>(
            im + (size_t)b0 * 3 * 80 * 80, c1w, c1b, n1g, n1b, c1o, 128, 3, 80, 80, 24);
        conv_bn_kernel<unsigned short><<<(1228800 + 255) / 256, 256, 0, stream>>>(
            c1o, c2w, c2b, n2g, n2b, c2o + (size_t)b0 * 24 * 20 * 20, 128, 24, 40, 40, 24);
    }
    conv_bn_kernel<unsigned short><<<(1228800 + 255) / 256, 256, 0, stream>>>(
        c2o, c3w, c3b, n3g, n3b, c3o, 512, 24, 20, 20, 24);
    conv_bn_kernel<unsigned short><<<(307200 + 255) / 256, 256, 0, stream>>>(
        c3o, c4w, c4b, n4g, n4b, c4o, 512, 24, 10, 10, 24);

    f2bf_kernel<<<256, 256, 0, stream>>>(g2w, wg2, 65536);
    f2bf_kernel<<<256, 256, 0, stream>>>(g3w, wg3, 65536);
    f2bf_kernel<<<256, 256, 0, stream>>>(g4w, wg4, 65536);

    prep_ab_kernel<<<512 * 25, 256, 0, stream>>>(c4o, g1w, A, Bv);
    prep_c_kernel<<<512, 256, 0, stream>>>(q, g1w, g1b, Cq);
    zero_kernel<<<512, 256, 0, stream>>>(xg, 131072);

    gmlp_kernel<<<512 * 5, 512, 0, stream>>>(A, Bv, Cq, wg2, g2b, wg3, g3b, wg4, g4b, xg);

    fc256_kernel<<<512, 256, 0, stream>>>(xg, f1w, f1b, t1);
    fc256_kernel<<<512, 256, 0, stream>>>(t1, f2w, f2b, t2);
    fc_out_kernel<<<512, 64, 0, stream>>>(t2, f3w, f3b, (float*)d_out);
}

// Round 4
// 619.541 us; speedup vs baseline: 3.3852x; 3.3852x over previous
//
#include <hip/hip_runtime.h>
#include <stdint.h>

typedef short     bf16x8  __attribute__((ext_vector_type(8)));
typedef float     f32x4   __attribute__((ext_vector_type(4)));
typedef unsigned short u16x8 __attribute__((ext_vector_type(8)));
typedef unsigned short u16x4 __attribute__((ext_vector_type(4)));

__device__ __forceinline__ float bf2f(unsigned short u) {
    union { unsigned int i; float f; } v; v.i = ((unsigned int)u) << 16; return v.f;
}
__device__ __forceinline__ unsigned short f2bf(float f) {
    union { float f; unsigned int i; } v; v.f = f;
    unsigned int x = v.i;
    return (unsigned short)((x + 0x7fffu + ((x >> 16) & 1u)) >> 16);
}

// ---------- conv1: im fp32 NCHW [B][3][80][80] -> bf16 NHWC [B][40][40][24] ----------
__global__ void conv1_kernel(const float* __restrict__ im, const float* __restrict__ w,
                             const float* __restrict__ bias, const float* __restrict__ bng,
                             const float* __restrict__ bnb, unsigned short* __restrict__ out)
{
    int idx = blockIdx.x * blockDim.x + threadIdx.x;
    if (idx >= 512 * 1600) return;
    int ow = idx % 40, oh = (idx / 40) % 40, b = idx / 1600;
    float acc[24];
    #pragma unroll
    for (int co = 0; co < 24; ++co) acc[co] = 0.f;
    const float* ip = im + (size_t)b * 3 * 6400;
    int ih0 = 2 * oh - 1, iw0 = 2 * ow - 1;
    #pragma unroll 1
    for (int ci = 0; ci < 3; ++ci) {
        const float* ipc = ip + ci * 6400;
        #pragma unroll 1
        for (int ky = 0; ky < 3; ++ky) {
            int ih = ih0 + ky; if (ih < 0) continue;
            #pragma unroll 1
            for (int kx = 0; kx < 3; ++kx) {
                int iw = iw0 + kx; if (iw < 0) continue;
                float x = ipc[ih * 80 + iw];
                int k = ci * 9 + ky * 3 + kx;      // uniform -> s_loads
                #pragma unroll
                for (int co = 0; co < 24; ++co) acc[co] += x * w[co * 27 + k];
            }
        }
    }
    unsigned short* op = out + (size_t)idx * 24;
    u16x4 o[6];
    #pragma unroll
    for (int co = 0; co < 24; ++co) {
        float scale = bng[co] * 0.9999950000374997f;
        o[co >> 2][co & 3] = f2bf((acc[co] + bias[co]) * scale + bnb[co]);
    }
    #pragma unroll
    for (int m = 0; m < 6; ++m) *(u16x4*)(op + m * 4) = o[m];
}

// ---------- convN: bf16 NHWC(24) -> bf16 NHWC(24), Cin=Cout=24 ----------
__global__ void convN_kernel(const unsigned short* __restrict__ in, const float* __restrict__ w,
                             const float* __restrict__ bias, const float* __restrict__ bng,
                             const float* __restrict__ bnb, unsigned short* __restrict__ out,
                             int B, int H, int W_, int OH, int OW)
{
    int idx = blockIdx.x * blockDim.x + threadIdx.x;
    if (idx >= B * OH * OW) return;
    int ow = idx % OW, oh = (idx / OW) % OH, b = idx / (OH * OW);
    float acc[24];
    #pragma unroll
    for (int co = 0; co < 24; ++co) acc[co] = 0.f;
    int ih0 = 2 * oh - 1, iw0 = 2 * ow - 1;
    #pragma unroll 1
    for (int ky = 0; ky < 3; ++ky) {
        int ih = ih0 + ky; if (ih < 0) continue;
        #pragma unroll 1
        for (int kx = 0; kx < 3; ++kx) {
            int iw = iw0 + kx; if (iw < 0) continue;
            const unsigned short* p = in + ((size_t)(b * H + ih) * W_ + iw) * 24;
            u16x4 v[6];
            #pragma unroll
            for (int m = 0; m < 6; ++m) v[m] = *(const u16x4*)(p + m * 4);
            float x[24];
            #pragma unroll
            for (int m = 0; m < 6; ++m)
                #pragma unroll
                for (int e = 0; e < 4; ++e) x[m * 4 + e] = bf2f(v[m][e]);
            int kb = ky * 3 + kx;
            #pragma unroll
            for (int ci = 0; ci < 24; ++ci) {
                float xv = x[ci];
                #pragma unroll
                for (int co = 0; co < 24; ++co)
                    acc[co] += xv * w[co * 216 + ci * 9 + kb];   // uniform -> s_loads
            }
        }
    }
    unsigned short* op = out + (size_t)idx * 24;
    u16x4 o[6];
    #pragma unroll
    for (int co = 0; co < 24; ++co) {
        float scale = bng[co] * 0.9999950000374997f;
        o[co >> 2][co & 3] = f2bf((acc[co] + bias[co]) * scale + bnb[co]);
    }
    #pragma unroll
    for (int m = 0; m < 6; ++m) *(u16x4*)(op + m * 4) = o[m];
}

// ---------- conv4: NHWC(24) -> Xf [B*25][32] bf16 (24 conv + 2 coords + 6 zeros) ----------
__global__ void conv4_kernel(const unsigned short* __restrict__ in, const float* __restrict__ w,
                             const float* __restrict__ bias, const float* __restrict__ bng,
                             const float* __restrict__ bnb, unsigned short* __restrict__ Xf)
{
    int idx = blockIdx.x * blockDim.x + threadIdx.x;
    if (idx >= 512 * 25) return;
    int ow = idx % 5, oh = (idx / 5) % 5, b = idx / 25;
    float acc[24];
    #pragma unroll
    for (int co = 0; co < 24; ++co) acc[co] = 0.f;
    int ih0 = 2 * oh - 1, iw0 = 2 * ow - 1;
    #pragma unroll 1
    for (int ky = 0; ky < 3; ++ky) {
        int ih = ih0 + ky; if (ih < 0) continue;
        #pragma unroll 1
        for (int kx = 0; kx < 3; ++kx) {
            int iw = iw0 + kx; if (iw < 0) continue;
            const unsigned short* p = in + ((size_t)(b * 10 + ih) * 10 + iw) * 24;
            u16x4 v[6];
            #pragma unroll
            for (int m = 0; m < 6; ++m) v[m] = *(const u16x4*)(p + m * 4);
            float x[24];
            #pragma unroll
            for (int m = 0; m < 6; ++m)
                #pragma unroll
                for (int e = 0; e < 4; ++e) x[m * 4 + e] = bf2f(v[m][e]);
            int kb = ky * 3 + kx;
            #pragma unroll
            for (int ci = 0; ci < 24; ++ci) {
                float xv = x[ci];
                #pragma unroll
                for (int co = 0; co < 24; ++co)
                    acc[co] += xv * w[co * 216 + ci * 9 + kb];
            }
        }
    }
    unsigned short* op = Xf + (size_t)idx * 32;
    u16x8 o[4];
    #pragma unroll
    for (int co = 0; co < 24; ++co) {
        float scale = bng[co] * 0.9999950000374997f;
        o[co >> 3][co & 7] = f2bf((acc[co] + bias[co]) * scale + bnb[co]);
    }
    o[3][0] = f2bf((oh - 2) * 0.5f);
    o[3][1] = f2bf((ow - 2) * 0.5f);
    #pragma unroll
    for (int e = 2; e < 8; ++e) o[3][e] = 0;
    #pragma unroll
    for (int m = 0; m < 4; ++m) *(u16x8*)(op + m * 8) = o[m];
}

// ---------- W1t[512][32] bf16: rows 0..255 = g1_w[u][0..25]; 256..511 = g1_w[u-256][26..51] ----------
__global__ void build_w1t_kernel(const float* __restrict__ g1w, unsigned short* __restrict__ W1t)
{
    int i = blockIdx.x * blockDim.x + threadIdx.x;
    if (i >= 16384) return;
    int u = i >> 5, k = i & 31;
    float v = 0.f;
    if (k < 26) v = (u < 256) ? g1w[u * 63 + k] : g1w[(u - 256) * 63 + 26 + k];
    W1t[i] = f2bf(v);
}

__global__ void f2bf_kernel(const float* __restrict__ in, unsigned short* __restrict__ out, int n)
{
    int i = blockIdx.x * blockDim.x + threadIdx.x;
    if (i < n) out[i] = f2bf(in[i]);
}

// ---------- prep GEMM: [12800 x 32] x [32 x 512] -> A[12800][256], Bv[12800][256] bf16 ----------
__global__ __launch_bounds__(512) void prep_gemm_kernel(
    const unsigned short* __restrict__ Xf, const unsigned short* __restrict__ W1t,
    unsigned short* __restrict__ A, unsigned short* __restrict__ Bv)
{
    int t = threadIdx.x, w8 = t >> 6, lane = t & 63;
    int rg = w8 & 3, cg = w8 >> 2;          // wave: 16 rows x 256 cols
    int lr = lane & 15, lh = lane >> 4;
    int row = blockIdx.x * 64 + rg * 16 + lr;
    bf16x8 af = *(const bf16x8*)(Xf + (size_t)row * 32 + lh * 8);
    f32x4 acc[16];
    #pragma unroll
    for (int ct = 0; ct < 16; ++ct) {
        int c0 = cg * 256 + ct * 16;
        bf16x8 bf = *(const bf16x8*)(W1t + (size_t)(c0 + lr) * 32 + lh * 8);
        acc[ct] = __builtin_amdgcn_mfma_f32_16x16x32_bf16(af, bf, (f32x4){0.f,0.f,0.f,0.f}, 0, 0, 0);
    }
    unsigned short* dst = (cg == 0) ? A : Bv;
    #pragma unroll
    for (int ct = 0; ct < 16; ++ct) {
        int col = ct * 16 + lr;
        #pragma unroll
        for (int reg = 0; reg < 4; ++reg) {
            int orow = blockIdx.x * 64 + rg * 16 + lh * 4 + reg;
            dst[(size_t)orow * 256 + col] = f2bf(acc[ct][reg]);
        }
    }
}

// Cq[b,u] = sum_k g1_w[u,52+k]*q[b,k] + g1_b[u]
__global__ void prep_c_kernel(const float* __restrict__ q, const float* __restrict__ g1w,
                              const float* __restrict__ g1b, float* __restrict__ Cq)
{
    int b = blockIdx.x, u = threadIdx.x;
    float acc = g1b[u];
    #pragma unroll
    for (int k = 0; k < 11; ++k)
        acc += g1w[u * 63 + 52 + k] * q[b * 11 + k];
    Cq[(size_t)b * 256 + u] = acc;
}

__global__ void zero_kernel(float* __restrict__ p, int n)
{
    int i = blockIdx.x * blockDim.x + threadIdx.x;
    if (i < n) p[i] = 0.f;
}

// ---------- fused g2/g3/g4 + pair-sum; single 64KB X buffer in-place ----------
__global__ __launch_bounds__(512, 4) void gmlp_kernel(
    const unsigned short* __restrict__ A, const unsigned short* __restrict__ Bv,
    const float* __restrict__ Cq,
    const unsigned short* __restrict__ w2, const float* __restrict__ b2,
    const unsigned short* __restrict__ w3, const float* __restrict__ b3,
    const unsigned short* __restrict__ w4, const float* __restrict__ b4,
    float* __restrict__ xg)
{
    __shared__ unsigned short X[128 * 256];   // 64 KB

    int blk  = blockIdx.x;
    int b    = blk / 5;
    int tile = blk % 5;
    int row0 = tile * 128;
    int t = threadIdx.x;

    // ---- h1 = relu(A[b,j] + Bv[b,i] + Cq[b]) into X (swizzled: sg = g ^ (row&15)) ----
    {
        int r = t >> 2;           // 0..127
        int quad = t & 3;
        int prow = row0 + r;
        if (prow < 625) {
            int i = prow / 25, j = prow % 25;
            const unsigned short* Ap = A  + ((size_t)b * 25 + j) * 256;
            const unsigned short* Bp = Bv + ((size_t)b * 25 + i) * 256;
            const float* Cp = Cq + (size_t)b * 256;
            #pragma unroll
            for (int k = 0; k < 8; ++k) {
                int g = quad + 4 * k;
                int c0 = g * 8;
                u16x8 av = *(const u16x8*)(Ap + c0);
                u16x8 bv = *(const u16x8*)(Bp + c0);
                f32x4 q0 = *(const f32x4*)(Cp + c0);
                f32x4 q1 = *(const f32x4*)(Cp + c0 + 4);
                u16x8 o;
                #pragma unroll
                for (int e = 0; e < 4; ++e) {
                    o[e]     = f2bf(fmaxf(bf2f(av[e])     + bf2f(bv[e])     + q0[e], 0.f));
                    o[4 + e] = f2bf(fmaxf(bf2f(av[4 + e]) + bf2f(bv[4 + e]) + q1[e], 0.f));
                }
                int sg = g ^ (r & 15);
                *(u16x8*)(X + r * 256 + sg * 8) = o;
            }
        } else {
            u16x8 z = {0,0,0,0,0,0,0,0};
            #pragma unroll
            for (int k = 0; k < 8; ++k) {
                int g = quad + 4 * k;
                int sg = g ^ (r & 15);
                *(u16x8*)(X + r * 256 + sg * 8) = z;
            }
        }
    }
    __syncthreads();

    int wid = t >> 6, lane = t & 63;
    int wr = (wid & 1) * 64;        // wave row base
    int wc = (wid >> 1) * 64;       // wave col base
    int lr = lane & 15, lh = lane >> 4;

    const unsigned short* Ws[3] = { w2, w3, w4 };
    const float* Bs[3] = { b2, b3, b4 };

    for (int L = 0; L < 3; ++L) {
        const unsigned short* W = Ws[L];
        float bias[4];
        #pragma unroll
        for (int cb = 0; cb < 4; ++cb) bias[cb] = Bs[L][wc + cb * 16 + lr];

        f32x4 acc[4][4];
        #pragma unroll
        for (int rb = 0; rb < 4; ++rb)
            #pragma unroll
            for (int cb = 0; cb < 4; ++cb)
                acc[rb][cb] = (f32x4){0.f, 0.f, 0.f, 0.f};

        for (int kk = 0; kk < 8; ++kk) {
            int k0 = kk * 32;
            bf16x8 af[4], bfr[4];
            #pragma unroll
            for (int rb = 0; rb < 4; ++rb) {
                int row = wr + rb * 16 + lr;
                int sg = (kk * 4 + lh) ^ (row & 15);
                af[rb] = *(const bf16x8*)(X + row * 256 + sg * 8);
            }
            #pragma unroll
            for (int cb = 0; cb < 4; ++cb) {
                int u = wc + cb * 16 + lr;
                bfr[cb] = *(const bf16x8*)(W + u * 256 + k0 + lh * 8);
            }
            #pragma unroll
            for (int rb = 0; rb < 4; ++rb)
                #pragma unroll
                for (int cb = 0; cb < 4; ++cb)
                    acc[rb][cb] = __builtin_amdgcn_mfma_f32_16x16x32_bf16(
                        af[rb], bfr[cb], acc[rb][cb], 0, 0, 0);
        }

        if (L < 2) {
            __syncthreads();   // everyone done reading X
            #pragma unroll
            for (int rb = 0; rb < 4; ++rb) {
                #pragma unroll
                for (int cb = 0; cb < 4; ++cb) {
                    #pragma unroll
                    for (int reg = 0; reg < 4; ++reg) {
                        float v = fmaxf(acc[rb][cb][reg] + bias[cb], 0.f);
                        int row = wr + rb * 16 + lh * 4 + reg;
                        int col = wc + cb * 16 + lr;
                        int sg = (col >> 3) ^ (row & 15);
                        X[row * 256 + sg * 8 + (col & 7)] = f2bf(v);
                    }
                }
            }
            __syncthreads();
        } else {
            float csum[4] = {0.f, 0.f, 0.f, 0.f};
            #pragma unroll
            for (int rb = 0; rb < 4; ++rb) {
                #pragma unroll
                for (int reg = 0; reg < 4; ++reg) {
                    int rowloc = wr + rb * 16 + lh * 4 + reg;
                    bool valid = (row0 + rowloc) < 625;
                    #pragma unroll
                    for (int cb = 0; cb < 4; ++cb) {
                        float v = fmaxf(acc[rb][cb][reg] + bias[cb], 0.f);
                        if (valid) csum[cb] += v;
                    }
                }
            }
            #pragma unroll
            for (int cb = 0; cb < 4; ++cb) {
                csum[cb] += __shfl_xor(csum[cb], 16);
                csum[cb] += __shfl_xor(csum[cb], 32);
            }
            if (lh == 0) {
                #pragma unroll
                for (int cb = 0; cb < 4; ++cb)
                    atomicAdd(&xg[(size_t)b * 256 + wc + cb * 16 + lr], csum[cb]);
            }
        }
    }
}

// ---------- f layers (fp32) ----------
__global__ void fc256_kernel(const float* __restrict__ in, const float* __restrict__ w,
                             const float* __restrict__ bias, float* __restrict__ out)
{
    __shared__ float xs[256];
    int b = blockIdx.x, u = threadIdx.x;
    xs[u] = in[(size_t)b * 256 + u];
    __syncthreads();
    float acc = bias[u];
    const f32x4* wr = (const f32x4*)(w + (size_t)u * 256);
    const f32x4* xr = (const f32x4*)xs;
    #pragma unroll 8
    for (int c = 0; c < 64; ++c) {
        f32x4 a = wr[c], x = xr[c];
        acc += a[0]*x[0] + a[1]*x[1] + a[2]*x[2] + a[3]*x[3];
    }
    out[(size_t)b * 256 + u] = fmaxf(acc, 0.f);
}

__global__ void fc_out_kernel(const float* __restrict__ in, const float* __restrict__ w,
                              const float* __restrict__ bias, float* __restrict__ out)
{
    __shared__ float xs[256];
    int b = blockIdx.x, t = threadIdx.x;
    for (int c = t; c < 256; c += 64) xs[c] = in[(size_t)b * 256 + c];
    __syncthreads();
    if (t < 10) {
        float acc = bias[t];
        const float* wr = w + t * 256;
        for (int c = 0; c < 256; ++c) acc += wr[c] * xs[c];
        out[b * 10 + t] = acc;
    }
}

// ---------- launch ----------
extern "C" void kernel_launch(void* const* d_in, const int* in_sizes, int n_in,
                              void* d_out, int out_size, void* d_ws, size_t ws_size,
                              hipStream_t stream)
{
    const float* im  = (const float*)d_in[0];
    const float* q   = (const float*)d_in[1];
    const float* c1w = (const float*)d_in[2];
    const float* c1b = (const float*)d_in[3];
    const float* n1g = (const float*)d_in[4];
    const float* n1b = (const float*)d_in[5];
    const float* c2w = (const float*)d_in[6];
    const float* c2b = (const float*)d_in[7];
    const float* n2g = (const float*)d_in[8];
    const float* n2b = (const float*)d_in[9];
    const float* c3w = (const float*)d_in[10];
    const float* c3b = (const float*)d_in[11];
    const float* n3g = (const float*)d_in[12];
    const float* n3b = (const float*)d_in[13];
    const float* c4w = (const float*)d_in[14];
    const float* c4b = (const float*)d_in[15];
    const float* n4g = (const float*)d_in[16];
    const float* n4b = (const float*)d_in[17];
    const float* g1w = (const float*)d_in[18];
    const float* g1b = (const float*)d_in[19];
    const float* g2w = (const float*)d_in[20];
    const float* g2b = (const float*)d_in[21];
    const float* g3w = (const float*)d_in[22];
    const float* g3b = (const float*)d_in[23];
    const float* g4w = (const float*)d_in[24];
    const float* g4b = (const float*)d_in[25];
    const float* f1w = (const float*)d_in[26];
    const float* f1b = (const float*)d_in[27];
    const float* f2w = (const float*)d_in[28];
    const float* f2b = (const float*)d_in[29];
    const float* f3w = (const float*)d_in[30];
    const float* f3b = (const float*)d_in[31];

    char* ws = (char*)d_ws;
    size_t off = 0;
    auto alloc = [&](size_t bytes) -> void* {
        void* p = ws + off;
        off += (bytes + 255) & ~(size_t)255;
        return p;
    };
    // big region: c1o [512*40*40*24] ushort = 39.3MB; after conv2 it is dead and
    // A / Bv / c3o / Xf live inside it (16.4MB total, disjoint offsets).
    unsigned short* c1o = (unsigned short*)alloc(19660800ull * 2);
    unsigned short* A   = c1o;                       // 3,276,800 u
    unsigned short* Bv  = c1o + 3276800;             // 3,276,800 u
    unsigned short* c3o = c1o + 6553600;             // 512*100*24 = 1,228,800 u
    unsigned short* Xf  = c1o + 7782400;             // 12800*32   =   409,600 u
    unsigned short* c2o = (unsigned short*)alloc(4915200ull * 2);   // 512*400*24
    unsigned short* W1t = (unsigned short*)alloc(16384ull * 2);
    unsigned short* wg2 = (unsigned short*)alloc(65536ull * 2);
    unsigned short* wg3 = (unsigned short*)alloc(65536ull * 2);
    unsigned short* wg4 = (unsigned short*)alloc(65536ull * 2);
    float* Cq  = (float*)alloc(131072ull * 4);
    float* xg  = (float*)alloc(131072ull * 4);
    float* t1  = (float*)alloc(131072ull * 4);
    float* t2  = (float*)alloc(131072ull * 4);

    conv1_kernel<<<(819200 + 255) / 256, 256, 0, stream>>>(im, c1w, c1b, n1g, n1b, c1o);
    convN_kernel<<<(204800 + 255) / 256, 256, 0, stream>>>(c1o, c2w, c2b, n2g, n2b, c2o, 512, 40, 40, 20, 20);
    convN_kernel<<<(51200  + 255) / 256, 256, 0, stream>>>(c2o, c3w, c3b, n3g, n3b, c3o, 512, 20, 20, 10, 10);
    conv4_kernel<<<(12800  + 255) / 256, 256, 0, stream>>>(c3o, c4w, c4b, n4g, n4b, Xf);

    build_w1t_kernel<<<64, 256, 0, stream>>>(g1w, W1t);
    f2bf_kernel<<<256, 256, 0, stream>>>(g2w, wg2, 65536);
    f2bf_kernel<<<256, 256, 0, stream>>>(g3w, wg3, 65536);
    f2bf_kernel<<<256, 256, 0, stream>>>(g4w, wg4, 65536);

    prep_gemm_kernel<<<200, 512, 0, stream>>>(Xf, W1t, A, Bv);
    prep_c_kernel<<<512, 256, 0, stream>>>(q, g1w, g1b, Cq);
    zero_kernel<<<512, 256, 0, stream>>>(xg, 131072);

    gmlp_kernel<<<512 * 5, 512, 0, stream>>>(A, Bv, Cq, wg2, g2b, wg3, g3b, wg4, g4b, xg);

    fc256_kernel<<<512, 256, 0, stream>>>(xg, f1w, f1b, t1);
    fc256_kernel<<<512, 256, 0, stream>>>(t1, f2w, f2b, t2);
    fc_out_kernel<<<512, 64, 0, stream>>>(t2, f3w, f3b, (float*)d_out);
}

// Round 5
// 482.872 us; speedup vs baseline: 4.3433x; 1.2830x over previous
//
#include <hip/hip_runtime.h>
#include <stdint.h>

typedef short     bf16x8  __attribute__((ext_vector_type(8)));
typedef float     f32x4   __attribute__((ext_vector_type(4)));
typedef unsigned short u16x8 __attribute__((ext_vector_type(8)));
typedef unsigned short u16x4 __attribute__((ext_vector_type(4)));

__device__ __forceinline__ float bf2f(unsigned short u) {
    union { unsigned int i; float f; } v; v.i = ((unsigned int)u) << 16; return v.f;
}
__device__ __forceinline__ unsigned short f2bf(float f) {
    union { float f; unsigned int i; } v; v.f = f;
    unsigned int x = v.i;
    return (unsigned short)((x + 0x7fffu + ((x >> 16) & 1u)) >> 16);
}

// ---------- conv1: im fp32 NCHW [B][3][80][80] -> bf16 NHWC [B][40][40][24] ----------
__global__ void conv1_kernel(const float* __restrict__ im, const float* __restrict__ w,
                             const float* __restrict__ bias, const float* __restrict__ bng,
                             const float* __restrict__ bnb, unsigned short* __restrict__ out)
{
    int idx = blockIdx.x * blockDim.x + threadIdx.x;
    if (idx >= 512 * 1600) return;
    int ow = idx % 40, oh = (idx / 40) % 40, b = idx / 1600;
    float acc[24];
    #pragma unroll
    for (int co = 0; co < 24; ++co) acc[co] = 0.f;
    const float* ip = im + (size_t)b * 3 * 6400;
    int ih0 = 2 * oh - 1, iw0 = 2 * ow - 1;
    #pragma unroll 1
    for (int ci = 0; ci < 3; ++ci) {
        const float* ipc = ip + ci * 6400;
        #pragma unroll 1
        for (int ky = 0; ky < 3; ++ky) {
            int ih = ih0 + ky; if (ih < 0) continue;
            #pragma unroll 1
            for (int kx = 0; kx < 3; ++kx) {
                int iw = iw0 + kx; if (iw < 0) continue;
                float x = ipc[ih * 80 + iw];
                int k = ci * 9 + ky * 3 + kx;      // uniform -> s_loads
                #pragma unroll
                for (int co = 0; co < 24; ++co) acc[co] += x * w[co * 27 + k];
            }
        }
    }
    unsigned short* op = out + (size_t)idx * 24;
    u16x4 o[6];
    #pragma unroll
    for (int co = 0; co < 24; ++co) {
        float scale = bng[co] * 0.9999950000374997f;
        o[co >> 2][co & 3] = f2bf((acc[co] + bias[co]) * scale + bnb[co]);
    }
    #pragma unroll
    for (int m = 0; m < 6; ++m) *(u16x4*)(op + m * 4) = o[m];
}

// ---------- convN: bf16 NHWC(24) -> bf16 NHWC(24), Cin=Cout=24 ----------
__global__ void convN_kernel(const unsigned short* __restrict__ in, const float* __restrict__ w,
                             const float* __restrict__ bias, const float* __restrict__ bng,
                             const float* __restrict__ bnb, unsigned short* __restrict__ out,
                             int B, int H, int W_, int OH, int OW)
{
    int idx = blockIdx.x * blockDim.x + threadIdx.x;
    if (idx >= B * OH * OW) return;
    int ow = idx % OW, oh = (idx / OW) % OH, b = idx / (OH * OW);
    float acc[24];
    #pragma unroll
    for (int co = 0; co < 24; ++co) acc[co] = 0.f;
    int ih0 = 2 * oh - 1, iw0 = 2 * ow - 1;
    #pragma unroll 1
    for (int ky = 0; ky < 3; ++ky) {
        int ih = ih0 + ky; if (ih < 0) continue;
        #pragma unroll 1
        for (int kx = 0; kx < 3; ++kx) {
            int iw = iw0 + kx; if (iw < 0) continue;
            const unsigned short* p = in + ((size_t)(b * H + ih) * W_ + iw) * 24;
            u16x4 v[6];
            #pragma unroll
            for (int m = 0; m < 6; ++m) v[m] = *(const u16x4*)(p + m * 4);
            float x[24];
            #pragma unroll
            for (int m = 0; m < 6; ++m)
                #pragma unroll
                for (int e = 0; e < 4; ++e) x[m * 4 + e] = bf2f(v[m][e]);
            int kb = ky * 3 + kx;
            #pragma unroll
            for (int ci = 0; ci < 24; ++ci) {
                float xv = x[ci];
                #pragma unroll
                for (int co = 0; co < 24; ++co)
                    acc[co] += xv * w[co * 216 + ci * 9 + kb];   // uniform -> s_loads
            }
        }
    }
    unsigned short* op = out + (size_t)idx * 24;
    u16x4 o[6];
    #pragma unroll
    for (int co = 0; co < 24; ++co) {
        float scale = bng[co] * 0.9999950000374997f;
        o[co >> 2][co & 3] = f2bf((acc[co] + bias[co]) * scale + bnb[co]);
    }
    #pragma unroll
    for (int m = 0; m < 6; ++m) *(u16x4*)(op + m * 4) = o[m];
}

// ---------- conv4: NHWC(24) -> Xf [B*25][32] bf16 (24 conv + 2 coords + 6 zeros) ----------
__global__ void conv4_kernel(const unsigned short* __restrict__ in, const float* __restrict__ w,
                             const float* __restrict__ bias, const float* __restrict__ bng,
                             const float* __restrict__ bnb, unsigned short* __restrict__ Xf)
{
    int idx = blockIdx.x * blockDim.x + threadIdx.x;
    if (idx >= 512 * 25) return;
    int ow = idx % 5, oh = (idx / 5) % 5, b = idx / 25;
    float acc[24];
    #pragma unroll
    for (int co = 0; co < 24; ++co) acc[co] = 0.f;
    int ih0 = 2 * oh - 1, iw0 = 2 * ow - 1;
    #pragma unroll 1
    for (int ky = 0; ky < 3; ++ky) {
        int ih = ih0 + ky; if (ih < 0) continue;
        #pragma unroll 1
        for (int kx = 0; kx < 3; ++kx) {
            int iw = iw0 + kx; if (iw < 0) continue;
            const unsigned short* p = in + ((size_t)(b * 10 + ih) * 10 + iw) * 24;
            u16x4 v[6];
            #pragma unroll
            for (int m = 0; m < 6; ++m) v[m] = *(const u16x4*)(p + m * 4);
            float x[24];
            #pragma unroll
            for (int m = 0; m < 6; ++m)
                #pragma unroll
                for (int e = 0; e < 4; ++e) x[m * 4 + e] = bf2f(v[m][e]);
            int kb = ky * 3 + kx;
            #pragma unroll
            for (int ci = 0; ci < 24; ++ci) {
                float xv = x[ci];
                #pragma unroll
                for (int co = 0; co < 24; ++co)
                    acc[co] += xv * w[co * 216 + ci * 9 + kb];
            }
        }
    }
    unsigned short* op = Xf + (size_t)idx * 32;
    u16x8 o[4];
    #pragma unroll
    for (int co = 0; co < 24; ++co) {
        float scale = bng[co] * 0.9999950000374997f;
        o[co >> 3][co & 7] = f2bf((acc[co] + bias[co]) * scale + bnb[co]);
    }
    o[3][0] = f2bf((oh - 2) * 0.5f);
    o[3][1] = f2bf((ow - 2) * 0.5f);
    #pragma unroll
    for (int e = 2; e < 8; ++e) o[3][e] = 0;
    #pragma unroll
    for (int m = 0; m < 4; ++m) *(u16x8*)(op + m * 8) = o[m];
}

// ---------- W1t[512][32] bf16: rows 0..255 = g1_w[u][0..25]; 256..511 = g1_w[u-256][26..51] ----------
__global__ void build_w1t_kernel(const float* __restrict__ g1w, unsigned short* __restrict__ W1t)
{
    int i = blockIdx.x * blockDim.x + threadIdx.x;
    if (i >= 16384) return;
    int u = i >> 5, k = i & 31;
    float v = 0.f;
    if (k < 26) v = (u < 256) ? g1w[u * 63 + k] : g1w[(u - 256) * 63 + 26 + k];
    W1t[i] = f2bf(v);
}

// ---------- g-weight transpose: w[u][256] fp32 -> wt[kk][u][32] bf16 (kk = k/32) ----------
// Lane-coalesced B-fragment loads: fragment (kk, u0..u0+15, k0+lh*8..) is 1KB contiguous.
__global__ void wt_kernel(const float* __restrict__ w, unsigned short* __restrict__ wt)
{
    int i = blockIdx.x * blockDim.x + threadIdx.x;   // 65536
    int kin = i & 31, u = (i >> 5) & 255, kk = i >> 13;
    wt[i] = f2bf(w[u * 256 + kk * 32 + kin]);
}

// ---------- prep GEMM: [12800 x 32] x [32 x 512] -> A[12800][256], Bv[12800][256] bf16 ----------
__global__ __launch_bounds__(512) void prep_gemm_kernel(
    const unsigned short* __restrict__ Xf, const unsigned short* __restrict__ W1t,
    unsigned short* __restrict__ A, unsigned short* __restrict__ Bv)
{
    int t = threadIdx.x, w8 = t >> 6, lane = t & 63;
    int rg = w8 & 3, cg = w8 >> 2;          // wave: 16 rows x 256 cols
    int lr = lane & 15, lh = lane >> 4;
    int row = blockIdx.x * 64 + rg * 16 + lr;
    bf16x8 af = *(const bf16x8*)(Xf + (size_t)row * 32 + lh * 8);
    f32x4 acc[16];
    #pragma unroll
    for (int ct = 0; ct < 16; ++ct) {
        int c0 = cg * 256 + ct * 16;
        bf16x8 bf = *(const bf16x8*)(W1t + (size_t)(c0 + lr) * 32 + lh * 8);
        acc[ct] = __builtin_amdgcn_mfma_f32_16x16x32_bf16(af, bf, (f32x4){0.f,0.f,0.f,0.f}, 0, 0, 0);
    }
    unsigned short* dst = (cg == 0) ? A : Bv;
    #pragma unroll
    for (int ct = 0; ct < 16; ++ct) {
        int col = ct * 16 + lr;
        #pragma unroll
        for (int reg = 0; reg < 4; ++reg) {
            int orow = blockIdx.x * 64 + rg * 16 + lh * 4 + reg;
            dst[(size_t)orow * 256 + col] = f2bf(acc[ct][reg]);
        }
    }
}

// Cq[b,u] = sum_k g1_w[u,52+k]*q[b,k] + g1_b[u]
__global__ void prep_c_kernel(const float* __restrict__ q, const float* __restrict__ g1w,
                              const float* __restrict__ g1b, float* __restrict__ Cq)
{
    int b = blockIdx.x, u = threadIdx.x;
    float acc = g1b[u];
    #pragma unroll
    for (int k = 0; k < 11; ++k)
        acc += g1w[u * 63 + 52 + k] * q[b * 11 + k];
    Cq[(size_t)b * 256 + u] = acc;
}

__global__ void zero_kernel(float* __restrict__ p, int n)
{
    int i = blockIdx.x * blockDim.x + threadIdx.x;
    if (i < n) p[i] = 0.f;
}

// ---------- fused g2/g3/g4 + pair-sum; single 64KB X buffer in-place ----------
// Weights in wt layout [kk][u][32].
__global__ __launch_bounds__(512, 2) void gmlp_kernel(
    const unsigned short* __restrict__ A, const unsigned short* __restrict__ Bv,
    const float* __restrict__ Cq,
    const unsigned short* __restrict__ w2, const float* __restrict__ b2,
    const unsigned short* __restrict__ w3, const float* __restrict__ b3,
    const unsigned short* __restrict__ w4, const float* __restrict__ b4,
    float* __restrict__ xg)
{
    __shared__ unsigned short X[128 * 256];   // 64 KB

    int blk  = blockIdx.x;
    int b    = blk / 5;
    int tile = blk % 5;
    int row0 = tile * 128;
    int t = threadIdx.x;

    // ---- h1 = relu(A[b,j] + Bv[b,i] + Cq[b]) into X (swizzled: sg = g ^ (row&15)) ----
    {
        int r = t >> 2;           // 0..127
        int quad = t & 3;
        int prow = row0 + r;
        if (prow < 625) {
            int i = prow / 25, j = prow % 25;
            const unsigned short* Ap = A  + ((size_t)b * 25 + j) * 256;
            const unsigned short* Bp = Bv + ((size_t)b * 25 + i) * 256;
            const float* Cp = Cq + (size_t)b * 256;
            #pragma unroll
            for (int k = 0; k < 8; ++k) {
                int g = quad + 4 * k;
                int c0 = g * 8;
                u16x8 av = *(const u16x8*)(Ap + c0);
                u16x8 bv = *(const u16x8*)(Bp + c0);
                f32x4 q0 = *(const f32x4*)(Cp + c0);
                f32x4 q1 = *(const f32x4*)(Cp + c0 + 4);
                u16x8 o;
                #pragma unroll
                for (int e = 0; e < 4; ++e) {
                    o[e]     = f2bf(fmaxf(bf2f(av[e])     + bf2f(bv[e])     + q0[e], 0.f));
                    o[4 + e] = f2bf(fmaxf(bf2f(av[4 + e]) + bf2f(bv[4 + e]) + q1[e], 0.f));
                }
                int sg = g ^ (r & 15);
                *(u16x8*)(X + r * 256 + sg * 8) = o;
            }
        } else {
            u16x8 z = {0,0,0,0,0,0,0,0};
            #pragma unroll
            for (int k = 0; k < 8; ++k) {
                int g = quad + 4 * k;
                int sg = g ^ (r & 15);
                *(u16x8*)(X + r * 256 + sg * 8) = z;
            }
        }
    }
    __syncthreads();

    int wid = t >> 6, lane = t & 63;
    int wr = (wid & 1) * 64;        // wave row base
    int wc = (wid >> 1) * 64;       // wave col base
    int lr = lane & 15, lh = lane >> 4;

    const unsigned short* Ws[3] = { w2, w3, w4 };
    const float* Bs[3] = { b2, b3, b4 };

    for (int L = 0; L < 3; ++L) {
        const unsigned short* W = Ws[L];
        float bias[4];
        #pragma unroll
        for (int cb = 0; cb < 4; ++cb) bias[cb] = Bs[L][wc + cb * 16 + lr];

        f32x4 acc[4][4];
        #pragma unroll
        for (int rb = 0; rb < 4; ++rb)
            #pragma unroll
            for (int cb = 0; cb < 4; ++cb)
                acc[rb][cb] = (f32x4){0.f, 0.f, 0.f, 0.f};

        for (int kk = 0; kk < 8; ++kk) {
            bf16x8 af[4], bfr[4];
            #pragma unroll
            for (int rb = 0; rb < 4; ++rb) {
                int row = wr + rb * 16 + lr;
                int sg = (kk * 4 + lh) ^ (row & 15);
                af[rb] = *(const bf16x8*)(X + row * 256 + sg * 8);
            }
            #pragma unroll
            for (int cb = 0; cb < 4; ++cb) {
                int u = wc + cb * 16 + lr;
                bfr[cb] = *(const bf16x8*)(W + (size_t)kk * 8192 + u * 32 + lh * 8);
            }
            #pragma unroll
            for (int rb = 0; rb < 4; ++rb)
                #pragma unroll
                for (int cb = 0; cb < 4; ++cb)
                    acc[rb][cb] = __builtin_amdgcn_mfma_f32_16x16x32_bf16(
                        af[rb], bfr[cb], acc[rb][cb], 0, 0, 0);
        }

        if (L < 2) {
            __syncthreads();   // everyone done reading X
            #pragma unroll
            for (int rb = 0; rb < 4; ++rb) {
                #pragma unroll
                for (int cb = 0; cb < 4; ++cb) {
                    #pragma unroll
                    for (int reg = 0; reg < 4; ++reg) {
                        float v = fmaxf(acc[rb][cb][reg] + bias[cb], 0.f);
                        int row = wr + rb * 16 + lh * 4 + reg;
                        int col = wc + cb * 16 + lr;
                        int sg = (col >> 3) ^ (row & 15);
                        X[row * 256 + sg * 8 + (col & 7)] = f2bf(v);
                    }
                }
            }
            __syncthreads();
        } else {
            float csum[4] = {0.f, 0.f, 0.f, 0.f};
            #pragma unroll
            for (int rb = 0; rb < 4; ++rb) {
                #pragma unroll
                for (int reg = 0; reg < 4; ++reg) {
                    int rowloc = wr + rb * 16 + lh * 4 + reg;
                    bool valid = (row0 + rowloc) < 625;
                    #pragma unroll
                    for (int cb = 0; cb < 4; ++cb) {
                        float v = fmaxf(acc[rb][cb][reg] + bias[cb], 0.f);
                        if (valid) csum[cb] += v;
                    }
                }
            }
            #pragma unroll
            for (int cb = 0; cb < 4; ++cb) {
                csum[cb] += __shfl_xor(csum[cb], 16);
                csum[cb] += __shfl_xor(csum[cb], 32);
            }
            if (lh == 0) {
                #pragma unroll
                for (int cb = 0; cb < 4; ++cb)
                    atomicAdd(&xg[(size_t)b * 256 + wc + cb * 16 + lr], csum[cb]);
            }
        }
    }
}

// ---------- f layers (fp32) ----------
__global__ void fc256_kernel(const float* __restrict__ in, const float* __restrict__ w,
                             const float* __restrict__ bias, float* __restrict__ out)
{
    __shared__ float xs[256];
    int b = blockIdx.x, u = threadIdx.x;
    xs[u] = in[(size_t)b * 256 + u];
    __syncthreads();
    float acc = bias[u];
    const f32x4* wr = (const f32x4*)(w + (size_t)u * 256);
    const f32x4* xr = (const f32x4*)xs;
    #pragma unroll 8
    for (int c = 0; c < 64; ++c) {
        f32x4 a = wr[c], x = xr[c];
        acc += a[0]*x[0] + a[1]*x[1] + a[2]*x[2] + a[3]*x[3];
    }
    out[(size_t)b * 256 + u] = fmaxf(acc, 0.f);
}

__global__ void fc_out_kernel(const float* __restrict__ in, const float* __restrict__ w,
                              const float* __restrict__ bias, float* __restrict__ out)
{
    __shared__ float xs[256];
    int b = blockIdx.x, t = threadIdx.x;
    for (int c = t; c < 256; c += 64) xs[c] = in[(size_t)b * 256 + c];
    __syncthreads();
    if (t < 10) {
        float acc = bias[t];
        const float* wr = w + t * 256;
        for (int c = 0; c < 256; ++c) acc += wr[c] * xs[c];
        out[b * 10 + t] = acc;
    }
}

// ---------- launch ----------
extern "C" void kernel_launch(void* const* d_in, const int* in_sizes, int n_in,
                              void* d_out, int out_size, void* d_ws, size_t ws_size,
                              hipStream_t stream)
{
    const float* im  = (const float*)d_in[0];
    const float* q   = (const float*)d_in[1];
    const float* c1w = (const float*)d_in[2];
    const float* c1b = (const float*)d_in[3];
    const float* n1g = (const float*)d_in[4];
    const float* n1b = (const float*)d_in[5];
    const float* c2w = (const float*)d_in[6];
    const float* c2b = (const float*)d_in[7];
    const float* n2g = (const float*)d_in[8];
    const float* n2b = (const float*)d_in[9];
    const float* c3w = (const float*)d_in[10];
    const float* c3b = (const float*)d_in[11];
    const float* n3g = (const float*)d_in[12];
    const float* n3b = (const float*)d_in[13];
    const float* c4w = (const float*)d_in[14];
    const float* c4b = (const float*)d_in[15];
    const float* n4g = (const float*)d_in[16];
    const float* n4b = (const float*)d_in[17];
    const float* g1w = (const float*)d_in[18];
    const float* g1b = (const float*)d_in[19];
    const float* g2w = (const float*)d_in[20];
    const float* g2b = (const float*)d_in[21];
    const float* g3w = (const float*)d_in[22];
    const float* g3b = (const float*)d_in[23];
    const float* g4w = (const float*)d_in[24];
    const float* g4b = (const float*)d_in[25];
    const float* f1w = (const float*)d_in[26];
    const float* f1b = (const float*)d_in[27];
    const float* f2w = (const float*)d_in[28];
    const float* f2b = (const float*)d_in[29];
    const float* f3w = (const float*)d_in[30];
    const float* f3b = (const float*)d_in[31];

    char* ws = (char*)d_ws;
    size_t off = 0;
    auto alloc = [&](size_t bytes) -> void* {
        void* p = ws + off;
        off += (bytes + 255) & ~(size_t)255;
        return p;
    };
    // big region: c1o [512*40*40*24] ushort = 39.3MB; after conv2 it is dead and
    // A / Bv / c3o / Xf live inside it (16.4MB total, disjoint offsets).
    unsigned short* c1o = (unsigned short*)alloc(19660800ull * 2);
    unsigned short* A   = c1o;                       // 3,276,800 u
    unsigned short* Bv  = c1o + 3276800;             // 3,276,800 u
    unsigned short* c3o = c1o + 6553600;             // 512*100*24 = 1,228,800 u
    unsigned short* Xf  = c1o + 7782400;             // 12800*32   =   409,600 u
    unsigned short* c2o = (unsigned short*)alloc(4915200ull * 2);   // 512*400*24
    unsigned short* W1t = (unsigned short*)alloc(16384ull * 2);
    unsigned short* wg2 = (unsigned short*)alloc(65536ull * 2);
    unsigned short* wg3 = (unsigned short*)alloc(65536ull * 2);
    unsigned short* wg4 = (unsigned short*)alloc(65536ull * 2);
    float* Cq  = (float*)alloc(131072ull * 4);
    float* xg  = (float*)alloc(131072ull * 4);
    float* t1  = (float*)alloc(131072ull * 4);
    float* t2  = (float*)alloc(131072ull * 4);

    conv1_kernel<<<(819200 + 255) / 256, 256, 0, stream>>>(im, c1w, c1b, n1g, n1b, c1o);
    convN_kernel<<<(204800 + 255) / 256, 256, 0, stream>>>(c1o, c2w, c2b, n2g, n2b, c2o, 512, 40, 40, 20, 20);
    convN_kernel<<<(51200  + 255) / 256, 256, 0, stream>>>(c2o, c3w, c3b, n3g, n3b, c3o, 512, 20, 20, 10, 10);
    conv4_kernel<<<(12800  + 255) / 256, 256, 0, stream>>>(c3o, c4w, c4b, n4g, n4b, Xf);

    build_w1t_kernel<<<64, 256, 0, stream>>>(g1w, W1t);
    wt_kernel<<<256, 256, 0, stream>>>(g2w, wg2);
    wt_kernel<<<256, 256, 0, stream>>>(g3w, wg3);
    wt_kernel<<<256, 256, 0, stream>>>(g4w, wg4);

    prep_gemm_kernel<<<200, 512, 0, stream>>>(Xf, W1t, A, Bv);
    prep_c_kernel<<<512, 256, 0, stream>>>(q, g1w, g1b, Cq);
    zero_kernel<<<512, 256, 0, stream>>>(xg, 131072);

    gmlp_kernel<<<512 * 5, 512, 0, stream>>>(A, Bv, Cq, wg2, g2b, wg3, g3b, wg4, g4b, xg);

    fc256_kernel<<<512, 256, 0, stream>>>(xg, f1w, f1b, t1);
    fc256_kernel<<<512, 256, 0, stream>>>(t1, f2w, f2b, t2);
    fc_out_kernel<<<512, 64, 0, stream>>>(t2, f3w, f3b, (float*)d_out);
}

// Round 6
// 475.316 us; speedup vs baseline: 4.4124x; 1.0159x over previous
//
#include <hip/hip_runtime.h>
#include <stdint.h>

typedef short     bf16x8  __attribute__((ext_vector_type(8)));
typedef float     f32x4   __attribute__((ext_vector_type(4)));
typedef unsigned short u16x8 __attribute__((ext_vector_type(8)));
typedef unsigned short u16x4 __attribute__((ext_vector_type(4)));

__device__ __forceinline__ float bf2f(unsigned short u) {
    union { unsigned int i; float f; } v; v.i = ((unsigned int)u) << 16; return v.f;
}
__device__ __forceinline__ unsigned short f2bf(float f) {
    union { float f; unsigned int i; } v; v.f = f;
    unsigned int x = v.i;
    return (unsigned short)((x + 0x7fffu + ((x >> 16) & 1u)) >> 16);
}

// ---------- conv1: im fp32 NCHW [B][3][80][80] -> bf16 NHWC [B][40][40][24] ----------
__global__ void conv1_kernel(const float* __restrict__ im, const float* __restrict__ w,
                             const float* __restrict__ bias, const float* __restrict__ bng,
                             const float* __restrict__ bnb, unsigned short* __restrict__ out)
{
    int idx = blockIdx.x * blockDim.x + threadIdx.x;
    if (idx >= 512 * 1600) return;
    int ow = idx % 40, oh = (idx / 40) % 40, b = idx / 1600;
    float acc[24];
    #pragma unroll
    for (int co = 0; co < 24; ++co) acc[co] = 0.f;
    const float* ip = im + (size_t)b * 3 * 6400;
    int ih0 = 2 * oh - 1, iw0 = 2 * ow - 1;
    #pragma unroll 1
    for (int ci = 0; ci < 3; ++ci) {
        const float* ipc = ip + ci * 6400;
        #pragma unroll 1
        for (int ky = 0; ky < 3; ++ky) {
            int ih = ih0 + ky; if (ih < 0) continue;
            #pragma unroll 1
            for (int kx = 0; kx < 3; ++kx) {
                int iw = iw0 + kx; if (iw < 0) continue;
                float x = ipc[ih * 80 + iw];
                int k = ci * 9 + ky * 3 + kx;      // uniform -> s_loads
                #pragma unroll
                for (int co = 0; co < 24; ++co) acc[co] += x * w[co * 27 + k];
            }
        }
    }
    unsigned short* op = out + (size_t)idx * 24;
    u16x4 o[6];
    #pragma unroll
    for (int co = 0; co < 24; ++co) {
        float scale = bng[co] * 0.9999950000374997f;
        o[co >> 2][co & 3] = f2bf((acc[co] + bias[co]) * scale + bnb[co]);
    }
    #pragma unroll
    for (int m = 0; m < 6; ++m) *(u16x4*)(op + m * 4) = o[m];
}

// ---------- convN: bf16 NHWC(24) -> bf16 NHWC(24), Cin=Cout=24 ----------
__global__ void convN_kernel(const unsigned short* __restrict__ in, const float* __restrict__ w,
                             const float* __restrict__ bias, const float* __restrict__ bng,
                             const float* __restrict__ bnb, unsigned short* __restrict__ out,
                             int B, int H, int W_, int OH, int OW)
{
    int idx = blockIdx.x * blockDim.x + threadIdx.x;
    if (idx >= B * OH * OW) return;
    int ow = idx % OW, oh = (idx / OW) % OH, b = idx / (OH * OW);
    float acc[24];
    #pragma unroll
    for (int co = 0; co < 24; ++co) acc[co] = 0.f;
    int ih0 = 2 * oh - 1, iw0 = 2 * ow - 1;
    #pragma unroll 1
    for (int ky = 0; ky < 3; ++ky) {
        int ih = ih0 + ky; if (ih < 0) continue;
        #pragma unroll 1
        for (int kx = 0; kx < 3; ++kx) {
            int iw = iw0 + kx; if (iw < 0) continue;
            const unsigned short* p = in + ((size_t)(b * H + ih) * W_ + iw) * 24;
            u16x4 v[6];
            #pragma unroll
            for (int m = 0; m < 6; ++m) v[m] = *(const u16x4*)(p + m * 4);
            float x[24];
            #pragma unroll
            for (int m = 0; m < 6; ++m)
                #pragma unroll
                for (int e = 0; e < 4; ++e) x[m * 4 + e] = bf2f(v[m][e]);
            int kb = ky * 3 + kx;
            #pragma unroll
            for (int ci = 0; ci < 24; ++ci) {
                float xv = x[ci];
                #pragma unroll
                for (int co = 0; co < 24; ++co)
                    acc[co] += xv * w[co * 216 + ci * 9 + kb];   // uniform -> s_loads
            }
        }
    }
    unsigned short* op = out + (size_t)idx * 24;
    u16x4 o[6];
    #pragma unroll
    for (int co = 0; co < 24; ++co) {
        float scale = bng[co] * 0.9999950000374997f;
        o[co >> 2][co & 3] = f2bf((acc[co] + bias[co]) * scale + bnb[co]);
    }
    #pragma unroll
    for (int m = 0; m < 6; ++m) *(u16x4*)(op + m * 4) = o[m];
}

// ---------- conv4: NHWC(24) -> Xf [B*25][32] bf16 (24 conv + 2 coords + 6 zeros) ----------
__global__ void conv4_kernel(const unsigned short* __restrict__ in, const float* __restrict__ w,
                             const float* __restrict__ bias, const float* __restrict__ bng,
                             const float* __restrict__ bnb, unsigned short* __restrict__ Xf)
{
    int idx = blockIdx.x * blockDim.x + threadIdx.x;
    if (idx >= 512 * 25) return;
    int ow = idx % 5, oh = (idx / 5) % 5, b = idx / 25;
    float acc[24];
    #pragma unroll
    for (int co = 0; co < 24; ++co) acc[co] = 0.f;
    int ih0 = 2 * oh - 1, iw0 = 2 * ow - 1;
    #pragma unroll 1
    for (int ky = 0; ky < 3; ++ky) {
        int ih = ih0 + ky; if (ih < 0) continue;
        #pragma unroll 1
        for (int kx = 0; kx < 3; ++kx) {
            int iw = iw0 + kx; if (iw < 0) continue;
            const unsigned short* p = in + ((size_t)(b * 10 + ih) * 10 + iw) * 24;
            u16x4 v[6];
            #pragma unroll
            for (int m = 0; m < 6; ++m) v[m] = *(const u16x4*)(p + m * 4);
            float x[24];
            #pragma unroll
            for (int m = 0; m < 6; ++m)
                #pragma unroll
                for (int e = 0; e < 4; ++e) x[m * 4 + e] = bf2f(v[m][e]);
            int kb = ky * 3 + kx;
            #pragma unroll
            for (int ci = 0; ci < 24; ++ci) {
                float xv = x[ci];
                #pragma unroll
                for (int co = 0; co < 24; ++co)
                    acc[co] += xv * w[co * 216 + ci * 9 + kb];
            }
        }
    }
    unsigned short* op = Xf + (size_t)idx * 32;
    u16x8 o[4];
    #pragma unroll
    for (int co = 0; co < 24; ++co) {
        float scale = bng[co] * 0.9999950000374997f;
        o[co >> 3][co & 7] = f2bf((acc[co] + bias[co]) * scale + bnb[co]);
    }
    o[3][0] = f2bf((oh - 2) * 0.5f);
    o[3][1] = f2bf((ow - 2) * 0.5f);
    #pragma unroll
    for (int e = 2; e < 8; ++e) o[3][e] = 0;
    #pragma unroll
    for (int m = 0; m < 4; ++m) *(u16x8*)(op + m * 8) = o[m];
}

// ---------- W1t[512][32] bf16 ----------
__global__ void build_w1t_kernel(const float* __restrict__ g1w, unsigned short* __restrict__ W1t)
{
    int i = blockIdx.x * blockDim.x + threadIdx.x;
    if (i >= 16384) return;
    int u = i >> 5, k = i & 31;
    float v = 0.f;
    if (k < 26) v = (u < 256) ? g1w[u * 63 + k] : g1w[(u - 256) * 63 + 26 + k];
    W1t[i] = f2bf(v);
}

// ---------- g-weight transpose: w[u][256] fp32 -> wt[kk][u][32] bf16 ----------
__global__ void wt_kernel(const float* __restrict__ w, unsigned short* __restrict__ wt)
{
    int i = blockIdx.x * blockDim.x + threadIdx.x;   // 65536
    int kin = i & 31, u = (i >> 5) & 255, kk = i >> 13;
    wt[i] = f2bf(w[u * 256 + kk * 32 + kin]);
}

// ---------- prep GEMM: [12800 x 32] x [32 x 512] -> A, Bv bf16 ----------
__global__ __launch_bounds__(512) void prep_gemm_kernel(
    const unsigned short* __restrict__ Xf, const unsigned short* __restrict__ W1t,
    unsigned short* __restrict__ A, unsigned short* __restrict__ Bv)
{
    int t = threadIdx.x, w8 = t >> 6, lane = t & 63;
    int rg = w8 & 3, cg = w8 >> 2;
    int lr = lane & 15, lh = lane >> 4;
    int row = blockIdx.x * 64 + rg * 16 + lr;
    bf16x8 af = *(const bf16x8*)(Xf + (size_t)row * 32 + lh * 8);
    f32x4 acc[16];
    #pragma unroll
    for (int ct = 0; ct < 16; ++ct) {
        int c0 = cg * 256 + ct * 16;
        bf16x8 bf = *(const bf16x8*)(W1t + (size_t)(c0 + lr) * 32 + lh * 8);
        acc[ct] = __builtin_amdgcn_mfma_f32_16x16x32_bf16(af, bf, (f32x4){0.f,0.f,0.f,0.f}, 0, 0, 0);
    }
    unsigned short* dst = (cg == 0) ? A : Bv;
    #pragma unroll
    for (int ct = 0; ct < 16; ++ct) {
        int col = ct * 16 + lr;
        #pragma unroll
        for (int reg = 0; reg < 4; ++reg) {
            int orow = blockIdx.x * 64 + rg * 16 + lh * 4 + reg;
            dst[(size_t)orow * 256 + col] = f2bf(acc[ct][reg]);
        }
    }
}

// Cq[b,u] = sum_k g1_w[u,52+k]*q[b,k] + g1_b[u]
__global__ void prep_c_kernel(const float* __restrict__ q, const float* __restrict__ g1w,
                              const float* __restrict__ g1b, float* __restrict__ Cq)
{
    int b = blockIdx.x, u = threadIdx.x;
    float acc = g1b[u];
    #pragma unroll
    for (int k = 0; k < 11; ++k)
        acc += g1w[u * 63 + 52 + k] * q[b * 11 + k];
    Cq[(size_t)b * 256 + u] = acc;
}

__global__ void zero_kernel(float* __restrict__ p, int n)
{
    int i = blockIdx.x * blockDim.x + threadIdx.x;
    if (i < n) p[i] = 0.f;
}

// ---------- fused g2/g3/g4 + pair-sum ----------
// 256 threads / 4 waves, 64-row tile, 32KB LDS -> target 4 blocks/CU.
// Wave = 64 rows x 64 cols (wc = wid*64). Weights in wt layout [kk][u][32],
// software-pipelined 2-deep (load kk+1 B-fragments before kk's MFMAs).
__global__ __launch_bounds__(256) void gmlp_kernel(
    const unsigned short* __restrict__ A, const unsigned short* __restrict__ Bv,
    const float* __restrict__ Cq,
    const unsigned short* __restrict__ w2, const float* __restrict__ b2,
    const unsigned short* __restrict__ w3, const float* __restrict__ b3,
    const unsigned short* __restrict__ w4, const float* __restrict__ b4,
    float* __restrict__ xg)
{
    __shared__ unsigned short X[64 * 256];   // 32 KB

    int blk  = blockIdx.x;
    int b    = blk / 10;
    int tile = blk % 10;
    int row0 = tile * 64;
    int t = threadIdx.x;

    // ---- h1 = relu(A[b,j] + Bv[b,i] + Cq[b]) into X (sg = g ^ (r&15)) ----
    {
        int r = t >> 2;           // 0..63
        int quad = t & 3;
        int prow = row0 + r;
        if (prow < 625) {
            int i = prow / 25, j = prow % 25;
            const unsigned short* Ap = A  + ((size_t)b * 25 + j) * 256;
            const unsigned short* Bp = Bv + ((size_t)b * 25 + i) * 256;
            const float* Cp = Cq + (size_t)b * 256;
            #pragma unroll
            for (int k = 0; k < 8; ++k) {
                int g = quad + 4 * k;
                int c0 = g * 8;
                u16x8 av = *(const u16x8*)(Ap + c0);
                u16x8 bv = *(const u16x8*)(Bp + c0);
                f32x4 q0 = *(const f32x4*)(Cp + c0);
                f32x4 q1 = *(const f32x4*)(Cp + c0 + 4);
                u16x8 o;
                #pragma unroll
                for (int e = 0; e < 4; ++e) {
                    o[e]     = f2bf(fmaxf(bf2f(av[e])     + bf2f(bv[e])     + q0[e], 0.f));
                    o[4 + e] = f2bf(fmaxf(bf2f(av[4 + e]) + bf2f(bv[4 + e]) + q1[e], 0.f));
                }
                int sg = g ^ (r & 15);
                *(u16x8*)(X + r * 256 + sg * 8) = o;
            }
        } else {
            u16x8 z = {0,0,0,0,0,0,0,0};
            #pragma unroll
            for (int k = 0; k < 8; ++k) {
                int g = quad + 4 * k;
                int sg = g ^ (r & 15);
                *(u16x8*)(X + r * 256 + sg * 8) = z;
            }
        }
    }
    __syncthreads();

    int wid = t >> 6, lane = t & 63;
    int wc = wid * 64;              // wave col base
    int lr = lane & 15, lh = lane >> 4;

    const unsigned short* Ws[3] = { w2, w3, w4 };
    const float* Bs[3] = { b2, b3, b4 };

    for (int L = 0; L < 3; ++L) {
        const unsigned short* W = Ws[L];
        float bias[4];
        #pragma unroll
        for (int cb = 0; cb < 4; ++cb) bias[cb] = Bs[L][wc + cb * 16 + lr];

        f32x4 acc[4][4];
        #pragma unroll
        for (int rb = 0; rb < 4; ++rb)
            #pragma unroll
            for (int cb = 0; cb < 4; ++cb)
                acc[rb][cb] = (f32x4){0.f, 0.f, 0.f, 0.f};

        // prologue: B-fragments for kk=0
        bf16x8 bcur[4], bnxt[4];
        #pragma unroll
        for (int cb = 0; cb < 4; ++cb)
            bcur[cb] = *(const bf16x8*)(W + (size_t)0 * 8192 + (wc + cb * 16 + lr) * 32 + lh * 8);

        #pragma unroll
        for (int kk = 0; kk < 8; ++kk) {
            if (kk < 7) {
                #pragma unroll
                for (int cb = 0; cb < 4; ++cb)
                    bnxt[cb] = *(const bf16x8*)(W + (size_t)(kk + 1) * 8192 + (wc + cb * 16 + lr) * 32 + lh * 8);
            }
            bf16x8 af[4];
            #pragma unroll
            for (int rb = 0; rb < 4; ++rb) {
                int row = rb * 16 + lr;
                int sg = (kk * 4 + lh) ^ (row & 15);
                af[rb] = *(const bf16x8*)(X + row * 256 + sg * 8);
            }
            #pragma unroll
            for (int rb = 0; rb < 4; ++rb)
                #pragma unroll
                for (int cb = 0; cb < 4; ++cb)
                    acc[rb][cb] = __builtin_amdgcn_mfma_f32_16x16x32_bf16(
                        af[rb], bcur[cb], acc[rb][cb], 0, 0, 0);
            #pragma unroll
            for (int cb = 0; cb < 4; ++cb) bcur[cb] = bnxt[cb];
        }

        if (L < 2) {
            __syncthreads();   // everyone done reading X
            #pragma unroll
            for (int rb = 0; rb < 4; ++rb) {
                #pragma unroll
                for (int cb = 0; cb < 4; ++cb) {
                    #pragma unroll
                    for (int reg = 0; reg < 4; ++reg) {
                        float v = fmaxf(acc[rb][cb][reg] + bias[cb], 0.f);
                        int row = rb * 16 + lh * 4 + reg;
                        int col = wc + cb * 16 + lr;
                        int sg = (col >> 3) ^ (row & 15);
                        X[row * 256 + sg * 8 + (col & 7)] = f2bf(v);
                    }
                }
            }
            __syncthreads();
        } else {
            float csum[4] = {0.f, 0.f, 0.f, 0.f};
            #pragma unroll
            for (int rb = 0; rb < 4; ++rb) {
                #pragma unroll
                for (int reg = 0; reg < 4; ++reg) {
                    int rowloc = rb * 16 + lh * 4 + reg;
                    bool valid = (row0 + rowloc) < 625;
                    #pragma unroll
                    for (int cb = 0; cb < 4; ++cb) {
                        float v = fmaxf(acc[rb][cb][reg] + bias[cb], 0.f);
                        if (valid) csum[cb] += v;
                    }
                }
            }
            #pragma unroll
            for (int cb = 0; cb < 4; ++cb) {
                csum[cb] += __shfl_xor(csum[cb], 16);
                csum[cb] += __shfl_xor(csum[cb], 32);
            }
            if (lh == 0) {
                #pragma unroll
                for (int cb = 0; cb < 4; ++cb)
                    atomicAdd(&xg[(size_t)b * 256 + wc + cb * 16 + lr], csum[cb]);
            }
        }
    }
}

// ---------- f layers (fp32) ----------
__global__ void fc256_kernel(const float* __restrict__ in, const float* __restrict__ w,
                             const float* __restrict__ bias, float* __restrict__ out)
{
    __shared__ float xs[256];
    int b = blockIdx.x, u = threadIdx.x;
    xs[u] = in[(size_t)b * 256 + u];
    __syncthreads();
    float acc = bias[u];
    const f32x4* wr = (const f32x4*)(w + (size_t)u * 256);
    const f32x4* xr = (const f32x4*)xs;
    #pragma unroll 8
    for (int c = 0; c < 64; ++c) {
        f32x4 a = wr[c], x = xr[c];
        acc += a[0]*x[0] + a[1]*x[1] + a[2]*x[2] + a[3]*x[3];
    }
    out[(size_t)b * 256 + u] = fmaxf(acc, 0.f);
}

__global__ void fc_out_kernel(const float* __restrict__ in, const float* __restrict__ w,
                              const float* __restrict__ bias, float* __restrict__ out)
{
    __shared__ float xs[256];
    int b = blockIdx.x, t = threadIdx.x;
    for (int c = t; c < 256; c += 64) xs[c] = in[(size_t)b * 256 + c];
    __syncthreads();
    if (t < 10) {
        float acc = bias[t];
        const float* wr = w + t * 256;
        for (int c = 0; c < 256; ++c) acc += wr[c] * xs[c];
        out[b * 10 + t] = acc;
    }
}

// ---------- launch ----------
extern "C" void kernel_launch(void* const* d_in, const int* in_sizes, int n_in,
                              void* d_out, int out_size, void* d_ws, size_t ws_size,
                              hipStream_t stream)
{
    const float* im  = (const float*)d_in[0];
    const float* q   = (const float*)d_in[1];
    const float* c1w = (const float*)d_in[2];
    const float* c1b = (const float*)d_in[3];
    const float* n1g = (const float*)d_in[4];
    const float* n1b = (const float*)d_in[5];
    const float* c2w = (const float*)d_in[6];
    const float* c2b = (const float*)d_in[7];
    const float* n2g = (const float*)d_in[8];
    const float* n2b = (const float*)d_in[9];
    const float* c3w = (const float*)d_in[10];
    const float* c3b = (const float*)d_in[11];
    const float* n3g = (const float*)d_in[12];
    const float* n3b = (const float*)d_in[13];
    const float* c4w = (const float*)d_in[14];
    const float* c4b = (const float*)d_in[15];
    const float* n4g = (const float*)d_in[16];
    const float* n4b = (const float*)d_in[17];
    const float* g1w = (const float*)d_in[18];
    const float* g1b = (const float*)d_in[19];
    const float* g2w = (const float*)d_in[20];
    const float* g2b = (const float*)d_in[21];
    const float* g3w = (const float*)d_in[22];
    const float* g3b = (const float*)d_in[23];
    const float* g4w = (const float*)d_in[24];
    const float* g4b = (const float*)d_in[25];
    const float* f1w = (const float*)d_in[26];
    const float* f1b = (const float*)d_in[27];
    const float* f2w = (const float*)d_in[28];
    const float* f2b = (const float*)d_in[29];
    const float* f3w = (const float*)d_in[30];
    const float* f3b = (const float*)d_in[31];

    char* ws = (char*)d_ws;
    size_t off = 0;
    auto alloc = [&](size_t bytes) -> void* {
        void* p = ws + off;
        off += (bytes + 255) & ~(size_t)255;
        return p;
    };
    unsigned short* c1o = (unsigned short*)alloc(19660800ull * 2);
    unsigned short* A   = c1o;                       // 3,276,800 u
    unsigned short* Bv  = c1o + 3276800;             // 3,276,800 u
    unsigned short* c3o = c1o + 6553600;             // 1,228,800 u
    unsigned short* Xf  = c1o + 7782400;             //   409,600 u
    unsigned short* c2o = (unsigned short*)alloc(4915200ull * 2);
    unsigned short* W1t = (unsigned short*)alloc(16384ull * 2);
    unsigned short* wg2 = (unsigned short*)alloc(65536ull * 2);
    unsigned short* wg3 = (unsigned short*)alloc(65536ull * 2);
    unsigned short* wg4 = (unsigned short*)alloc(65536ull * 2);
    float* Cq  = (float*)alloc(131072ull * 4);
    float* xg  = (float*)alloc(131072ull * 4);
    float* t1  = (float*)alloc(131072ull * 4);
    float* t2  = (float*)alloc(131072ull * 4);

    conv1_kernel<<<(819200 + 255) / 256, 256, 0, stream>>>(im, c1w, c1b, n1g, n1b, c1o);
    convN_kernel<<<(204800 + 255) / 256, 256, 0, stream>>>(c1o, c2w, c2b, n2g, n2b, c2o, 512, 40, 40, 20, 20);
    convN_kernel<<<(51200  + 255) / 256, 256, 0, stream>>>(c2o, c3w, c3b, n3g, n3b, c3o, 512, 20, 20, 10, 10);
    conv4_kernel<<<(12800  + 255) / 256, 256, 0, stream>>>(c3o, c4w, c4b, n4g, n4b, Xf);

    build_w1t_kernel<<<64, 256, 0, stream>>>(g1w, W1t);
    wt_kernel<<<256, 256, 0, stream>>>(g2w, wg2);
    wt_kernel<<<256, 256, 0, stream>>>(g3w, wg3);
    wt_kernel<<<256, 256, 0, stream>>>(g4w, wg4);

    prep_gemm_kernel<<<200, 512, 0, stream>>>(Xf, W1t, A, Bv);
    prep_c_kernel<<<512, 256, 0, stream>>>(q, g1w, g1b, Cq);
    zero_kernel<<<512, 256, 0, stream>>>(xg, 131072);

    gmlp_kernel<<<512 * 10, 256, 0, stream>>>(A, Bv, Cq, wg2, g2b, wg3, g3b, wg4, g4b, xg);

    fc256_kernel<<<512, 256, 0, stream>>>(xg, f1w, f1b, t1);
    fc256_kernel<<<512, 256, 0, stream>>>(t1, f2w, f2b, t2);
    fc_out_kernel<<<512, 64, 0, stream>>>(t2, f3w, f3b, (float*)d_out);
}

// Round 7
// 444.992 us; speedup vs baseline: 4.7130x; 1.0681x over previous
//
#include <hip/hip_runtime.h>
#include <stdint.h>

typedef short     bf16x8  __attribute__((ext_vector_type(8)));
typedef float     f32x4   __attribute__((ext_vector_type(4)));
typedef unsigned short u16x8 __attribute__((ext_vector_type(8)));
typedef unsigned short u16x4 __attribute__((ext_vector_type(4)));
typedef unsigned int   u32x4 __attribute__((ext_vector_type(4)));

__device__ __forceinline__ float bf2f(unsigned short u) {
    union { unsigned int i; float f; } v; v.i = ((unsigned int)u) << 16; return v.f;
}
__device__ __forceinline__ unsigned short f2bf(float f) {
    union { float f; unsigned int i; } v; v.f = f;
    unsigned int x = v.i;
    return (unsigned short)((x + 0x7fffu + ((x >> 16) & 1u)) >> 16);
}
// packed f32x2 -> bf16x2 (RNE), low word = lo
__device__ __forceinline__ unsigned int cvtpk(float lo, float hi) {
    unsigned int r;
    asm("v_cvt_pk_bf16_f32 %0, %1, %2" : "=v"(r) : "v"(lo), "v"(hi));
    return r;
}

// ---------- conv1: im fp32 NCHW [B][3][80][80] -> bf16 NHWC [B][40][40][24] ----------
__global__ void conv1_kernel(const float* __restrict__ im, const float* __restrict__ w,
                             const float* __restrict__ bias, const float* __restrict__ bng,
                             const float* __restrict__ bnb, unsigned short* __restrict__ out)
{
    int idx = blockIdx.x * blockDim.x + threadIdx.x;
    if (idx >= 512 * 1600) return;
    int ow = idx % 40, oh = (idx / 40) % 40, b = idx / 1600;
    float acc[24];
    #pragma unroll
    for (int co = 0; co < 24; ++co) acc[co] = 0.f;
    const float* ip = im + (size_t)b * 3 * 6400;
    int ih0 = 2 * oh - 1, iw0 = 2 * ow - 1;
    #pragma unroll 1
    for (int ci = 0; ci < 3; ++ci) {
        const float* ipc = ip + ci * 6400;
        #pragma unroll 1
        for (int ky = 0; ky < 3; ++ky) {
            int ih = ih0 + ky; if (ih < 0) continue;
            #pragma unroll 1
            for (int kx = 0; kx < 3; ++kx) {
                int iw = iw0 + kx; if (iw < 0) continue;
                float x = ipc[ih * 80 + iw];
                int k = ci * 9 + ky * 3 + kx;
                #pragma unroll
                for (int co = 0; co < 24; ++co) acc[co] += x * w[co * 27 + k];
            }
        }
    }
    unsigned short* op = out + (size_t)idx * 24;
    u16x4 o[6];
    #pragma unroll
    for (int co = 0; co < 24; ++co) {
        float scale = bng[co] * 0.9999950000374997f;
        o[co >> 2][co & 3] = f2bf((acc[co] + bias[co]) * scale + bnb[co]);
    }
    #pragma unroll
    for (int m = 0; m < 6; ++m) *(u16x4*)(op + m * 4) = o[m];
}

// ---------- convN: bf16 NHWC(24) -> bf16 NHWC(24) ----------
__global__ void convN_kernel(const unsigned short* __restrict__ in, const float* __restrict__ w,
                             const float* __restrict__ bias, const float* __restrict__ bng,
                             const float* __restrict__ bnb, unsigned short* __restrict__ out,
                             int B, int H, int W_, int OH, int OW)
{
    int idx = blockIdx.x * blockDim.x + threadIdx.x;
    if (idx >= B * OH * OW) return;
    int ow = idx % OW, oh = (idx / OW) % OH, b = idx / (OH * OW);
    float acc[24];
    #pragma unroll
    for (int co = 0; co < 24; ++co) acc[co] = 0.f;
    int ih0 = 2 * oh - 1, iw0 = 2 * ow - 1;
    #pragma unroll 1
    for (int ky = 0; ky < 3; ++ky) {
        int ih = ih0 + ky; if (ih < 0) continue;
        #pragma unroll 1
        for (int kx = 0; kx < 3; ++kx) {
            int iw = iw0 + kx; if (iw < 0) continue;
            const unsigned short* p = in + ((size_t)(b * H + ih) * W_ + iw) * 24;
            u16x4 v[6];
            #pragma unroll
            for (int m = 0; m < 6; ++m) v[m] = *(const u16x4*)(p + m * 4);
            float x[24];
            #pragma unroll
            for (int m = 0; m < 6; ++m)
                #pragma unroll
                for (int e = 0; e < 4; ++e) x[m * 4 + e] = bf2f(v[m][e]);
            int kb = ky * 3 + kx;
            #pragma unroll
            for (int ci = 0; ci < 24; ++ci) {
                float xv = x[ci];
                #pragma unroll
                for (int co = 0; co < 24; ++co)
                    acc[co] += xv * w[co * 216 + ci * 9 + kb];
            }
        }
    }
    unsigned short* op = out + (size_t)idx * 24;
    u16x4 o[6];
    #pragma unroll
    for (int co = 0; co < 24; ++co) {
        float scale = bng[co] * 0.9999950000374997f;
        o[co >> 2][co & 3] = f2bf((acc[co] + bias[co]) * scale + bnb[co]);
    }
    #pragma unroll
    for (int m = 0; m < 6; ++m) *(u16x4*)(op + m * 4) = o[m];
}

// ---------- conv4: NHWC(24) -> Xf [B*25][32] bf16 ----------
__global__ void conv4_kernel(const unsigned short* __restrict__ in, const float* __restrict__ w,
                             const float* __restrict__ bias, const float* __restrict__ bng,
                             const float* __restrict__ bnb, unsigned short* __restrict__ Xf)
{
    int idx = blockIdx.x * blockDim.x + threadIdx.x;
    if (idx >= 512 * 25) return;
    int ow = idx % 5, oh = (idx / 5) % 5, b = idx / 25;
    float acc[24];
    #pragma unroll
    for (int co = 0; co < 24; ++co) acc[co] = 0.f;
    int ih0 = 2 * oh - 1, iw0 = 2 * ow - 1;
    #pragma unroll 1
    for (int ky = 0; ky < 3; ++ky) {
        int ih = ih0 + ky; if (ih < 0) continue;
        #pragma unroll 1
        for (int kx = 0; kx < 3; ++kx) {
            int iw = iw0 + kx; if (iw < 0) continue;
            const unsigned short* p = in + ((size_t)(b * 10 + ih) * 10 + iw) * 24;
            u16x4 v[6];
            #pragma unroll
            for (int m = 0; m < 6; ++m) v[m] = *(const u16x4*)(p + m * 4);
            float x[24];
            #pragma unroll
            for (int m = 0; m < 6; ++m)
                #pragma unroll
                for (int e = 0; e < 4; ++e) x[m * 4 + e] = bf2f(v[m][e]);
            int kb = ky * 3 + kx;
            #pragma unroll
            for (int ci = 0; ci < 24; ++ci) {
                float xv = x[ci];
                #pragma unroll
                for (int co = 0; co < 24; ++co)
                    acc[co] += xv * w[co * 216 + ci * 9 + kb];
            }
        }
    }
    unsigned short* op = Xf + (size_t)idx * 32;
    u16x8 o[4];
    #pragma unroll
    for (int co = 0; co < 24; ++co) {
        float scale = bng[co] * 0.9999950000374997f;
        o[co >> 3][co & 7] = f2bf((acc[co] + bias[co]) * scale + bnb[co]);
    }
    o[3][0] = f2bf((oh - 2) * 0.5f);
    o[3][1] = f2bf((ow - 2) * 0.5f);
    #pragma unroll
    for (int e = 2; e < 8; ++e) o[3][e] = 0;
    #pragma unroll
    for (int m = 0; m < 4; ++m) *(u16x8*)(op + m * 8) = o[m];
}

// ---------- prep_misc: W1t + wt(g2,g3,g4) + zero(xg) + Cq, one launch ----------
__global__ void prep_misc_kernel(const float* __restrict__ g1w, const float* __restrict__ g1b,
                                 const float* __restrict__ g2w, const float* __restrict__ g3w,
                                 const float* __restrict__ g4w, const float* __restrict__ q,
                                 unsigned short* __restrict__ W1t,
                                 unsigned short* __restrict__ wg2, unsigned short* __restrict__ wg3,
                                 unsigned short* __restrict__ wg4,
                                 float* __restrict__ xg, float* __restrict__ Cq)
{
    int blk = blockIdx.x, t = threadIdx.x;
    if (blk < 64) {                               // W1t [512][32]
        int i = blk * 256 + t;
        int u = i >> 5, k = i & 31;
        float v = 0.f;
        if (k < 26) v = (u < 256) ? g1w[u * 63 + k] : g1w[(u - 256) * 63 + 26 + k];
        W1t[i] = f2bf(v);
    } else if (blk < 832) {                       // wt transpose for g2/g3/g4
        int s = blk - 64;
        int which = s >> 8;                       // 0,1,2
        int i = (s & 255) * 256 + t;
        int kin = i & 31, u = (i >> 5) & 255, kk = i >> 13;
        const float* w = (which == 0) ? g2w : (which == 1) ? g3w : g4w;
        unsigned short* wt = (which == 0) ? wg2 : (which == 1) ? wg3 : wg4;
        wt[i] = f2bf(w[u * 256 + kk * 32 + kin]);
    } else if (blk < 1344) {                      // zero xg
        xg[(blk - 832) * 256 + t] = 0.f;
    } else {                                      // Cq[b][u]
        int b = blk - 1344, u = t;
        float acc = g1b[u];
        #pragma unroll
        for (int k = 0; k < 11; ++k)
            acc += g1w[u * 63 + 52 + k] * q[b * 11 + k];
        Cq[(size_t)b * 256 + u] = acc;
    }
}

// ---------- prep GEMM: Xf[12800x32] x W1t -> A(+Cq folded), Bv bf16 ----------
__global__ __launch_bounds__(512) void prep_gemm_kernel(
    const unsigned short* __restrict__ Xf, const unsigned short* __restrict__ W1t,
    const float* __restrict__ Cq,
    unsigned short* __restrict__ A, unsigned short* __restrict__ Bv)
{
    int t = threadIdx.x, w8 = t >> 6, lane = t & 63;
    int rg = w8 & 3, cg = w8 >> 2;
    int lr = lane & 15, lh = lane >> 4;
    int row = blockIdx.x * 64 + rg * 16 + lr;
    bf16x8 af = *(const bf16x8*)(Xf + (size_t)row * 32 + lh * 8);
    f32x4 acc[16];
    #pragma unroll
    for (int ct = 0; ct < 16; ++ct) {
        int c0 = cg * 256 + ct * 16;
        bf16x8 bf = *(const bf16x8*)(W1t + (size_t)(c0 + lr) * 32 + lh * 8);
        acc[ct] = __builtin_amdgcn_mfma_f32_16x16x32_bf16(af, bf, (f32x4){0.f,0.f,0.f,0.f}, 0, 0, 0);
    }
    unsigned short* dst = (cg == 0) ? A : Bv;
    #pragma unroll
    for (int ct = 0; ct < 16; ++ct) {
        int col = ct * 16 + lr;
        #pragma unroll
        for (int reg = 0; reg < 4; ++reg) {
            int orow = blockIdx.x * 64 + rg * 16 + lh * 4 + reg;
            float v = acc[ct][reg];
            if (cg == 0) v += Cq[(orow / 25) * 256 + col];   // fold Cq into A
            dst[(size_t)orow * 256 + col] = f2bf(v);
        }
    }
}

// ---------- gemm_k: one 64x256x256 K-loop; SWAP selects D orientation ----------
template<bool SWAP>
__device__ __forceinline__ void gemm_k(const unsigned short* __restrict__ W,
                                       const unsigned short* X,
                                       int lr, int lh, int wc, f32x4 acc[4][4])
{
    bf16x8 bcur[4], bnxt[4];
    #pragma unroll
    for (int cb = 0; cb < 4; ++cb)
        bcur[cb] = *(const bf16x8*)(W + (wc + cb * 16 + lr) * 32 + lh * 8);
    #pragma unroll
    for (int kk = 0; kk < 8; ++kk) {
        if (kk < 7) {
            #pragma unroll
            for (int cb = 0; cb < 4; ++cb)
                bnxt[cb] = *(const bf16x8*)(W + (size_t)(kk + 1) * 8192 + (wc + cb * 16 + lr) * 32 + lh * 8);
        }
        bf16x8 af[4];
        #pragma unroll
        for (int rb = 0; rb < 4; ++rb) {
            int row = rb * 16 + lr;
            int sg = (kk * 4 + lh) ^ (row & 15);
            af[rb] = *(const bf16x8*)(X + row * 256 + sg * 8);
        }
        #pragma unroll
        for (int rb = 0; rb < 4; ++rb)
            #pragma unroll
            for (int cb = 0; cb < 4; ++cb)
                acc[rb][cb] = SWAP
                    ? __builtin_amdgcn_mfma_f32_16x16x32_bf16(bcur[cb], af[rb], acc[rb][cb], 0, 0, 0)
                    : __builtin_amdgcn_mfma_f32_16x16x32_bf16(af[rb], bcur[cb], acc[rb][cb], 0, 0, 0);
        #pragma unroll
        for (int cb = 0; cb < 4; ++cb) bcur[cb] = bnxt[cb];
    }
}

// ---------- fused g2/g3/g4 + pair-sum ----------
// 256 thr / 4 waves, 64-row tile, 32KB LDS. g2,g3 swapped (D=[u][prow]) ->
// epilogue = cvt_pk pairs + one b64 swizzled LDS store per tile. g4 unswapped.
__global__ __launch_bounds__(256) void gmlp_kernel(
    const unsigned short* __restrict__ A, const unsigned short* __restrict__ Bv,
    const unsigned short* __restrict__ w2, const float* __restrict__ b2,
    const unsigned short* __restrict__ w3, const float* __restrict__ b3,
    const unsigned short* __restrict__ w4, const float* __restrict__ b4,
    float* __restrict__ xg)
{
    __shared__ unsigned short X[64 * 256];   // 32 KB

    int blk  = blockIdx.x;
    int b    = blk / 10;
    int tile = blk % 10;
    int row0 = tile * 64;
    int t = threadIdx.x;

    // ---- h1 = relu(A'[b,j] + Bv[b,i]) into X (sg = g ^ (r&15)); Cq already in A'
    {
        int r = t >> 2, quad = t & 3;
        int prow = row0 + r;
        if (prow < 625) {
            int i = prow / 25, j = prow % 25;
            const unsigned short* Ap = A  + ((size_t)b * 25 + j) * 256;
            const unsigned short* Bp = Bv + ((size_t)b * 25 + i) * 256;
            #pragma unroll
            for (int k = 0; k < 8; ++k) {
                int g = quad + 4 * k;
                int c0 = g * 8;
                u16x8 av = *(const u16x8*)(Ap + c0);
                u16x8 bv = *(const u16x8*)(Bp + c0);
                float v[8];
                #pragma unroll
                for (int e = 0; e < 8; ++e)
                    v[e] = fmaxf(bf2f(av[e]) + bf2f(bv[e]), 0.f);
                u32x4 o = { cvtpk(v[0], v[1]), cvtpk(v[2], v[3]),
                            cvtpk(v[4], v[5]), cvtpk(v[6], v[7]) };
                int sg = g ^ (r & 15);
                *(u32x4*)(X + r * 256 + sg * 8) = o;
            }
        } else {
            u32x4 z = {0, 0, 0, 0};
            #pragma unroll
            for (int k = 0; k < 8; ++k) {
                int g = quad + 4 * k;
                int sg = g ^ (r & 15);
                *(u32x4*)(X + r * 256 + sg * 8) = z;
            }
        }
    }
    __syncthreads();

    int wid = t >> 6, lane = t & 63;
    int wc = wid * 64;
    int lr = lane & 15, lh = lane >> 4;

    // ---- g2, g3 (swapped orientation) ----
    const unsigned short* Wsw[2] = { w2, w3 };
    const float* Bsw[2] = { b2, b3 };
    #pragma unroll 1
    for (int L = 0; L < 2; ++L) {
        f32x4 acc[4][4];
        #pragma unroll
        for (int rb = 0; rb < 4; ++rb)
            #pragma unroll
            for (int cb = 0; cb < 4; ++cb) acc[rb][cb] = (f32x4){0.f,0.f,0.f,0.f};
        gemm_k<true>(Wsw[L], X, lr, lh, wc, acc);

        // bias along u = wc + cb*16 + lh*4 + reg
        f32x4 bsw[4];
        #pragma unroll
        for (int cb = 0; cb < 4; ++cb)
            bsw[cb] = *(const f32x4*)(Bsw[L] + wc + cb * 16 + lh * 4);

        __syncthreads();   // all waves done reading X
        #pragma unroll
        for (int rb = 0; rb < 4; ++rb) {
            int prow = rb * 16 + lr;
            #pragma unroll
            for (int cb = 0; cb < 4; ++cb) {
                float v0 = fmaxf(acc[rb][cb][0] + bsw[cb][0], 0.f);
                float v1 = fmaxf(acc[rb][cb][1] + bsw[cb][1], 0.f);
                float v2 = fmaxf(acc[rb][cb][2] + bsw[cb][2], 0.f);
                float v3 = fmaxf(acc[rb][cb][3] + bsw[cb][3], 0.f);
                unsigned int w0 = cvtpk(v0, v1), w1 = cvtpk(v2, v3);
                int u0 = wc + cb * 16 + lh * 4;
                int sg = (u0 >> 3) ^ (prow & 15);
                unsigned int* dst = (unsigned int*)(X + prow * 256 + sg * 8 + (u0 & 7));
                dst[0] = w0; dst[1] = w1;
            }
        }
        __syncthreads();
    }

    // ---- g4 (unswapped) + masked pair-sum ----
    {
        f32x4 acc[4][4];
        #pragma unroll
        for (int rb = 0; rb < 4; ++rb)
            #pragma unroll
            for (int cb = 0; cb < 4; ++cb) acc[rb][cb] = (f32x4){0.f,0.f,0.f,0.f};
        gemm_k<false>(w4, X, lr, lh, wc, acc);

        float bias[4];
        #pragma unroll
        for (int cb = 0; cb < 4; ++cb) bias[cb] = b4[wc + cb * 16 + lr];

        float csum[4] = {0.f, 0.f, 0.f, 0.f};
        #pragma unroll
        for (int rb = 0; rb < 4; ++rb) {
            #pragma unroll
            for (int reg = 0; reg < 4; ++reg) {
                int rowloc = rb * 16 + lh * 4 + reg;
                bool valid = (row0 + rowloc) < 625;
                #pragma unroll
                for (int cb = 0; cb < 4; ++cb) {
                    float v = fmaxf(acc[rb][cb][reg] + bias[cb], 0.f);
                    if (valid) csum[cb] += v;
                }
            }
        }
        #pragma unroll
        for (int cb = 0; cb < 4; ++cb) {
            csum[cb] += __shfl_xor(csum[cb], 16);
            csum[cb] += __shfl_xor(csum[cb], 32);
        }
        if (lh == 0) {
            #pragma unroll
            for (int cb = 0; cb < 4; ++cb)
                atomicAdd(&xg[(size_t)b * 256 + wc + cb * 16 + lr], csum[cb]);
        }
    }
}

// ---------- fused f1/f2/f3 ----------
__global__ void fc_fused_kernel(const float* __restrict__ xg,
                                const float* __restrict__ f1w, const float* __restrict__ f1b,
                                const float* __restrict__ f2w, const float* __restrict__ f2b,
                                const float* __restrict__ f3w, const float* __restrict__ f3b,
                                float* __restrict__ out)
{
    __shared__ float xs[256];
    __shared__ float ys[256];
    int b = blockIdx.x, u = threadIdx.x;
    xs[u] = xg[(size_t)b * 256 + u];
    __syncthreads();
    {
        float a = f1b[u];
        const f32x4* wr = (const f32x4*)(f1w + (size_t)u * 256);
        const f32x4* xr = (const f32x4*)xs;
        #pragma unroll 8
        for (int c = 0; c < 64; ++c) {
            f32x4 w = wr[c], x = xr[c];
            a += w[0]*x[0] + w[1]*x[1] + w[2]*x[2] + w[3]*x[3];
        }
        ys[u] = fmaxf(a, 0.f);
    }
    __syncthreads();
    {
        float a = f2b[u];
        const f32x4* wr = (const f32x4*)(f2w + (size_t)u * 256);
        const f32x4* xr = (const f32x4*)ys;
        #pragma unroll 8
        for (int c = 0; c < 64; ++c) {
            f32x4 w = wr[c], x = xr[c];
            a += w[0]*x[0] + w[1]*x[1] + w[2]*x[2] + w[3]*x[3];
        }
        xs[u] = fmaxf(a, 0.f);
    }
    __syncthreads();
    if (u < 10) {
        float a = f3b[u];
        const f32x4* wr = (const f32x4*)(f3w + (size_t)u * 256);
        const f32x4* xr = (const f32x4*)xs;
        for (int c = 0; c < 64; ++c) {
            f32x4 w = wr[c], x = xr[c];
            a += w[0]*x[0] + w[1]*x[1] + w[2]*x[2] + w[3]*x[3];
        }
        out[b * 10 + u] = a;
    }
}

// ---------- launch ----------
extern "C" void kernel_launch(void* const* d_in, const int* in_sizes, int n_in,
                              void* d_out, int out_size, void* d_ws, size_t ws_size,
                              hipStream_t stream)
{
    const float* im  = (const float*)d_in[0];
    const float* q   = (const float*)d_in[1];
    const float* c1w = (const float*)d_in[2];
    const float* c1b = (const float*)d_in[3];
    const float* n1g = (const float*)d_in[4];
    const float* n1b = (const float*)d_in[5];
    const float* c2w = (const float*)d_in[6];
    const float* c2b = (const float*)d_in[7];
    const float* n2g = (const float*)d_in[8];
    const float* n2b = (const float*)d_in[9];
    const float* c3w = (const float*)d_in[10];
    const float* c3b = (const float*)d_in[11];
    const float* n3g = (const float*)d_in[12];
    const float* n3b = (const float*)d_in[13];
    const float* c4w = (const float*)d_in[14];
    const float* c4b = (const float*)d_in[15];
    const float* n4g = (const float*)d_in[16];
    const float* n4b = (const float*)d_in[17];
    const float* g1w = (const float*)d_in[18];
    const float* g1b = (const float*)d_in[19];
    const float* g2w = (const float*)d_in[20];
    const float* g2b = (const float*)d_in[21];
    const float* g3w = (const float*)d_in[22];
    const float* g3b = (const float*)d_in[23];
    const float* g4w = (const float*)d_in[24];
    const float* g4b = (const float*)d_in[25];
    const float* f1w = (const float*)d_in[26];
    const float* f1b = (const float*)d_in[27];
    const float* f2w = (const float*)d_in[28];
    const float* f2b = (const float*)d_in[29];
    const float* f3w = (const float*)d_in[30];
    const float* f3b = (const float*)d_in[31];

    char* ws = (char*)d_ws;
    size_t off = 0;
    auto alloc = [&](size_t bytes) -> void* {
        void* p = ws + off;
        off += (bytes + 255) & ~(size_t)255;
        return p;
    };
    unsigned short* c1o = (unsigned short*)alloc(19660800ull * 2);
    unsigned short* A   = c1o;                       // 3,276,800 u
    unsigned short* Bv  = c1o + 3276800;             // 3,276,800 u
    unsigned short* c3o = c1o + 6553600;             // 1,228,800 u
    unsigned short* Xf  = c1o + 7782400;             //   409,600 u
    unsigned short* c2o = (unsigned short*)alloc(4915200ull * 2);
    unsigned short* W1t = (unsigned short*)alloc(16384ull * 2);
    unsigned short* wg2 = (unsigned short*)alloc(65536ull * 2);
    unsigned short* wg3 = (unsigned short*)alloc(65536ull * 2);
    unsigned short* wg4 = (unsigned short*)alloc(65536ull * 2);
    float* Cq  = (float*)alloc(131072ull * 4);
    float* xg  = (float*)alloc(131072ull * 4);

    conv1_kernel<<<(819200 + 255) / 256, 256, 0, stream>>>(im, c1w, c1b, n1g, n1b, c1o);
    convN_kernel<<<(204800 + 255) / 256, 256, 0, stream>>>(c1o, c2w, c2b, n2g, n2b, c2o, 512, 40, 40, 20, 20);
    convN_kernel<<<(51200  + 255) / 256, 256, 0, stream>>>(c2o, c3w, c3b, n3g, n3b, c3o, 512, 20, 20, 10, 10);
    conv4_kernel<<<(12800  + 255) / 256, 256, 0, stream>>>(c3o, c4w, c4b, n4g, n4b, Xf);

    prep_misc_kernel<<<1856, 256, 0, stream>>>(g1w, g1b, g2w, g3w, g4w, q,
                                               W1t, wg2, wg3, wg4, xg, Cq);

    prep_gemm_kernel<<<200, 512, 0, stream>>>(Xf, W1t, Cq, A, Bv);

    gmlp_kernel<<<512 * 10, 256, 0, stream>>>(A, Bv, wg2, g2b, wg3, g3b, wg4, g4b, xg);

    fc_fused_kernel<<<512, 256, 0, stream>>>(xg, f1w, f1b, f2w, f2b, f3w, f3b, (float*)d_out);
}

// Round 8
// 406.347 us; speedup vs baseline: 5.1613x; 1.0951x over previous
//
#include <hip/hip_runtime.h>
#include <stdint.h>

typedef short     bf16x8  __attribute__((ext_vector_type(8)));
typedef float     f32x4   __attribute__((ext_vector_type(4)));
typedef unsigned short u16x8 __attribute__((ext_vector_type(8)));
typedef unsigned short u16x4 __attribute__((ext_vector_type(4)));
typedef unsigned int   u32x4 __attribute__((ext_vector_type(4)));

__device__ __forceinline__ float bf2f(unsigned short u) {
    union { unsigned int i; float f; } v; v.i = ((unsigned int)u) << 16; return v.f;
}
__device__ __forceinline__ unsigned short f2bf(float f) {
    union { float f; unsigned int i; } v; v.f = f;
    unsigned int x = v.i;
    return (unsigned short)((x + 0x7fffu + ((x >> 16) & 1u)) >> 16);
}
__device__ __forceinline__ unsigned int cvtpk(float lo, float hi) {
    unsigned int r;
    asm("v_cvt_pk_bf16_f32 %0, %1, %2" : "=v"(r) : "v"(lo), "v"(hi));
    return r;
}

// ---------- conv1: im fp32 NCHW [B][3][80][80] -> bf16 NHWC [B][40][40][24] ----------
__global__ void conv1_kernel(const float* __restrict__ im, const float* __restrict__ w,
                             const float* __restrict__ bias, const float* __restrict__ bng,
                             const float* __restrict__ bnb, unsigned short* __restrict__ out)
{
    int idx = blockIdx.x * blockDim.x + threadIdx.x;
    if (idx >= 512 * 1600) return;
    int ow = idx % 40, oh = (idx / 40) % 40, b = idx / 1600;
    float acc[24];
    #pragma unroll
    for (int co = 0; co < 24; ++co) acc[co] = 0.f;
    const float* ip = im + (size_t)b * 3 * 6400;
    int ih0 = 2 * oh - 1, iw0 = 2 * ow - 1;
    #pragma unroll 1
    for (int ci = 0; ci < 3; ++ci) {
        const float* ipc = ip + ci * 6400;
        #pragma unroll 1
        for (int ky = 0; ky < 3; ++ky) {
            int ih = ih0 + ky; if (ih < 0) continue;
            #pragma unroll 1
            for (int kx = 0; kx < 3; ++kx) {
                int iw = iw0 + kx; if (iw < 0) continue;
                float x = ipc[ih * 80 + iw];
                int k = ci * 9 + ky * 3 + kx;
                #pragma unroll
                for (int co = 0; co < 24; ++co) acc[co] += x * w[co * 27 + k];
            }
        }
    }
    unsigned short* op = out + (size_t)idx * 24;
    u16x4 o[6];
    #pragma unroll
    for (int co = 0; co < 24; ++co) {
        float scale = bng[co] * 0.9999950000374997f;
        o[co >> 2][co & 3] = f2bf((acc[co] + bias[co]) * scale + bnb[co]);
    }
    #pragma unroll
    for (int m = 0; m < 6; ++m) *(u16x4*)(op + m * 4) = o[m];
}

// ---------- convN: bf16 NHWC(24) -> bf16 NHWC(24) ----------
__global__ void convN_kernel(const unsigned short* __restrict__ in, const float* __restrict__ w,
                             const float* __restrict__ bias, const float* __restrict__ bng,
                             const float* __restrict__ bnb, unsigned short* __restrict__ out,
                             int B, int H, int W_, int OH, int OW)
{
    int idx = blockIdx.x * blockDim.x + threadIdx.x;
    if (idx >= B * OH * OW) return;
    int ow = idx % OW, oh = (idx / OW) % OH, b = idx / (OH * OW);
    float acc[24];
    #pragma unroll
    for (int co = 0; co < 24; ++co) acc[co] = 0.f;
    int ih0 = 2 * oh - 1, iw0 = 2 * ow - 1;
    #pragma unroll 1
    for (int ky = 0; ky < 3; ++ky) {
        int ih = ih0 + ky; if (ih < 0) continue;
        #pragma unroll 1
        for (int kx = 0; kx < 3; ++kx) {
            int iw = iw0 + kx; if (iw < 0) continue;
            const unsigned short* p = in + ((size_t)(b * H + ih) * W_ + iw) * 24;
            u16x4 v[6];
            #pragma unroll
            for (int m = 0; m < 6; ++m) v[m] = *(const u16x4*)(p + m * 4);
            float x[24];
            #pragma unroll
            for (int m = 0; m < 6; ++m)
                #pragma unroll
                for (int e = 0; e < 4; ++e) x[m * 4 + e] = bf2f(v[m][e]);
            int kb = ky * 3 + kx;
            #pragma unroll
            for (int ci = 0; ci < 24; ++ci) {
                float xv = x[ci];
                #pragma unroll
                for (int co = 0; co < 24; ++co)
                    acc[co] += xv * w[co * 216 + ci * 9 + kb];
            }
        }
    }
    unsigned short* op = out + (size_t)idx * 24;
    u16x4 o[6];
    #pragma unroll
    for (int co = 0; co < 24; ++co) {
        float scale = bng[co] * 0.9999950000374997f;
        o[co >> 2][co & 3] = f2bf((acc[co] + bias[co]) * scale + bnb[co]);
    }
    #pragma unroll
    for (int m = 0; m < 6; ++m) *(u16x4*)(op + m * 4) = o[m];
}

// ---------- conv4: NHWC(24) -> Xf [B*25][32] bf16 ----------
__global__ void conv4_kernel(const unsigned short* __restrict__ in, const float* __restrict__ w,
                             const float* __restrict__ bias, const float* __restrict__ bng,
                             const float* __restrict__ bnb, unsigned short* __restrict__ Xf)
{
    int idx = blockIdx.x * blockDim.x + threadIdx.x;
    if (idx >= 512 * 25) return;
    int ow = idx % 5, oh = (idx / 5) % 5, b = idx / 25;
    float acc[24];
    #pragma unroll
    for (int co = 0; co < 24; ++co) acc[co] = 0.f;
    int ih0 = 2 * oh - 1, iw0 = 2 * ow - 1;
    #pragma unroll 1
    for (int ky = 0; ky < 3; ++ky) {
        int ih = ih0 + ky; if (ih < 0) continue;
        #pragma unroll 1
        for (int kx = 0; kx < 3; ++kx) {
            int iw = iw0 + kx; if (iw < 0) continue;
            const unsigned short* p = in + ((size_t)(b * 10 + ih) * 10 + iw) * 24;
            u16x4 v[6];
            #pragma unroll
            for (int m = 0; m < 6; ++m) v[m] = *(const u16x4*)(p + m * 4);
            float x[24];
            #pragma unroll
            for (int m = 0; m < 6; ++m)
                #pragma unroll
                for (int e = 0; e < 4; ++e) x[m * 4 + e] = bf2f(v[m][e]);
            int kb = ky * 3 + kx;
            #pragma unroll
            for (int ci = 0; ci < 24; ++ci) {
                float xv = x[ci];
                #pragma unroll
                for (int co = 0; co < 24; ++co)
                    acc[co] += xv * w[co * 216 + ci * 9 + kb];
            }
        }
    }
    unsigned short* op = Xf + (size_t)idx * 32;
    u16x8 o[4];
    #pragma unroll
    for (int co = 0; co < 24; ++co) {
        float scale = bng[co] * 0.9999950000374997f;
        o[co >> 3][co & 7] = f2bf((acc[co] + bias[co]) * scale + bnb[co]);
    }
    o[3][0] = f2bf((oh - 2) * 0.5f);
    o[3][1] = f2bf((ow - 2) * 0.5f);
    #pragma unroll
    for (int e = 2; e < 8; ++e) o[3][e] = 0;
    #pragma unroll
    for (int m = 0; m < 4; ++m) *(u16x8*)(op + m * 8) = o[m];
}

// ---------- prep_misc: W1t + wt(g2,g3,g4) + zero(xg) + Cq ----------
__global__ void prep_misc_kernel(const float* __restrict__ g1w, const float* __restrict__ g1b,
                                 const float* __restrict__ g2w, const float* __restrict__ g3w,
                                 const float* __restrict__ g4w, const float* __restrict__ q,
                                 unsigned short* __restrict__ W1t,
                                 unsigned short* __restrict__ wg2, unsigned short* __restrict__ wg3,
                                 unsigned short* __restrict__ wg4,
                                 float* __restrict__ xg, float* __restrict__ Cq)
{
    int blk = blockIdx.x, t = threadIdx.x;
    if (blk < 64) {
        int i = blk * 256 + t;
        int u = i >> 5, k = i & 31;
        float v = 0.f;
        if (k < 26) v = (u < 256) ? g1w[u * 63 + k] : g1w[(u - 256) * 63 + 26 + k];
        W1t[i] = f2bf(v);
    } else if (blk < 832) {
        int s = blk - 64;
        int which = s >> 8;
        int i = (s & 255) * 256 + t;
        int kin = i & 31, u = (i >> 5) & 255, kk = i >> 13;
        const float* w = (which == 0) ? g2w : (which == 1) ? g3w : g4w;
        unsigned short* wt = (which == 0) ? wg2 : (which == 1) ? wg3 : wg4;
        wt[i] = f2bf(w[u * 256 + kk * 32 + kin]);
    } else if (blk < 1344) {
        xg[(blk - 832) * 256 + t] = 0.f;
    } else {
        int b = blk - 1344, u = t;
        float acc = g1b[u];
        #pragma unroll
        for (int k = 0; k < 11; ++k)
            acc += g1w[u * 63 + 52 + k] * q[b * 11 + k];
        Cq[(size_t)b * 256 + u] = acc;
    }
}

// ---------- prep GEMM: Xf[12800x32] x W1t -> A(+Cq folded), Bv bf16 ----------
__global__ __launch_bounds__(512) void prep_gemm_kernel(
    const unsigned short* __restrict__ Xf, const unsigned short* __restrict__ W1t,
    const float* __restrict__ Cq,
    unsigned short* __restrict__ A, unsigned short* __restrict__ Bv)
{
    int t = threadIdx.x, w8 = t >> 6, lane = t & 63;
    int rg = w8 & 3, cg = w8 >> 2;
    int lr = lane & 15, lh = lane >> 4;
    int row = blockIdx.x * 64 + rg * 16 + lr;
    bf16x8 af = *(const bf16x8*)(Xf + (size_t)row * 32 + lh * 8);
    f32x4 acc[16];
    #pragma unroll
    for (int ct = 0; ct < 16; ++ct) {
        int c0 = cg * 256 + ct * 16;
        bf16x8 bf = *(const bf16x8*)(W1t + (size_t)(c0 + lr) * 32 + lh * 8);
        acc[ct] = __builtin_amdgcn_mfma_f32_16x16x32_bf16(af, bf, (f32x4){0.f,0.f,0.f,0.f}, 0, 0, 0);
    }
    unsigned short* dst = (cg == 0) ? A : Bv;
    #pragma unroll
    for (int ct = 0; ct < 16; ++ct) {
        int col = ct * 16 + lr;
        #pragma unroll
        for (int reg = 0; reg < 4; ++reg) {
            int orow = blockIdx.x * 64 + rg * 16 + lh * 4 + reg;
            float v = acc[ct][reg];
            if (cg == 0) v += Cq[(orow / 25) * 256 + col];
            dst[(size_t)orow * 256 + col] = f2bf(v);
        }
    }
}

// ---------- gemm_k over 128 rows: wave = 128 rows x 64 cols ----------
template<bool SWAP>
__device__ __forceinline__ void gemm_k128(const unsigned short* __restrict__ W,
                                          const unsigned short* X,
                                          int lr, int lh, int wc, f32x4 acc[8][4])
{
    bf16x8 bcur[4], bnxt[4];
    #pragma unroll
    for (int cb = 0; cb < 4; ++cb)
        bcur[cb] = *(const bf16x8*)(W + (wc + cb * 16 + lr) * 32 + lh * 8);
    #pragma unroll
    for (int kk = 0; kk < 8; ++kk) {
        if (kk < 7) {
            #pragma unroll
            for (int cb = 0; cb < 4; ++cb)
                bnxt[cb] = *(const bf16x8*)(W + (size_t)(kk + 1) * 8192 + (wc + cb * 16 + lr) * 32 + lh * 8);
        }
        #pragma unroll
        for (int rb = 0; rb < 8; ++rb) {
            int row = rb * 16 + lr;
            int sg = (kk * 4 + lh) ^ (row & 15);
            bf16x8 af = *(const bf16x8*)(X + row * 256 + sg * 8);
            #pragma unroll
            for (int cb = 0; cb < 4; ++cb)
                acc[rb][cb] = SWAP
                    ? __builtin_amdgcn_mfma_f32_16x16x32_bf16(bcur[cb], af, acc[rb][cb], 0, 0, 0)
                    : __builtin_amdgcn_mfma_f32_16x16x32_bf16(af, bcur[cb], acc[rb][cb], 0, 0, 0);
        }
        #pragma unroll
        for (int cb = 0; cb < 4; ++cb) bcur[cb] = bnxt[cb];
    }
}

// ---------- fused g2/g3/g4 + pair-sum; 128-row tile, 64KB LDS, 4 waves ----------
__global__ __launch_bounds__(256, 2) void gmlp_kernel(
    const unsigned short* __restrict__ A, const unsigned short* __restrict__ Bv,
    const unsigned short* __restrict__ w2, const float* __restrict__ b2,
    const unsigned short* __restrict__ w3, const float* __restrict__ b3,
    const unsigned short* __restrict__ w4, const float* __restrict__ b4,
    float* __restrict__ xg)
{
    __shared__ unsigned short X[128 * 256];   // 64 KB

    int blk  = blockIdx.x;
    int b    = blk / 5;
    int tile = blk % 5;
    int row0 = tile * 128;
    int t = threadIdx.x;

    // ---- h1 = relu(A'[b,j] + Bv[b,i]) into X (sg = g ^ (r&15)); Cq folded in A'
    {
        int r = t >> 1, half = t & 1;
        int prow = row0 + r;
        if (prow < 625) {
            int i = prow / 25, j = prow % 25;
            const unsigned short* Ap = A  + ((size_t)b * 25 + j) * 256;
            const unsigned short* Bp = Bv + ((size_t)b * 25 + i) * 256;
            #pragma unroll
            for (int k = 0; k < 16; ++k) {
                int g = half + 2 * k;
                int c0 = g * 8;
                u16x8 av = *(const u16x8*)(Ap + c0);
                u16x8 bv = *(const u16x8*)(Bp + c0);
                float v[8];
                #pragma unroll
                for (int e = 0; e < 8; ++e)
                    v[e] = fmaxf(bf2f(av[e]) + bf2f(bv[e]), 0.f);
                u32x4 o = { cvtpk(v[0], v[1]), cvtpk(v[2], v[3]),
                            cvtpk(v[4], v[5]), cvtpk(v[6], v[7]) };
                int sg = g ^ (r & 15);
                *(u32x4*)(X + r * 256 + sg * 8) = o;
            }
        } else {
            u32x4 z = {0, 0, 0, 0};
            #pragma unroll
            for (int k = 0; k < 16; ++k) {
                int g = half + 2 * k;
                int sg = g ^ (r & 15);
                *(u32x4*)(X + r * 256 + sg * 8) = z;
            }
        }
    }
    __syncthreads();

    int wid = t >> 6, lane = t & 63;
    int wc = wid * 64;
    int lr = lane & 15, lh = lane >> 4;

    // ---- g2, g3 (swapped: D rows = u, cols = prow) ----
    const unsigned short* Wsw[2] = { w2, w3 };
    const float* Bsw[2] = { b2, b3 };
    #pragma unroll 1
    for (int L = 0; L < 2; ++L) {
        f32x4 acc[8][4];
        #pragma unroll
        for (int rb = 0; rb < 8; ++rb)
            #pragma unroll
            for (int cb = 0; cb < 4; ++cb) acc[rb][cb] = (f32x4){0.f,0.f,0.f,0.f};
        gemm_k128<true>(Wsw[L], X, lr, lh, wc, acc);

        f32x4 bsw[4];
        #pragma unroll
        for (int cb = 0; cb < 4; ++cb)
            bsw[cb] = *(const f32x4*)(Bsw[L] + wc + cb * 16 + lh * 4);

        __syncthreads();
        #pragma unroll
        for (int rb = 0; rb < 8; ++rb) {
            int prow = rb * 16 + lr;
            #pragma unroll
            for (int cb = 0; cb < 4; ++cb) {
                float v0 = fmaxf(acc[rb][cb][0] + bsw[cb][0], 0.f);
                float v1 = fmaxf(acc[rb][cb][1] + bsw[cb][1], 0.f);
                float v2 = fmaxf(acc[rb][cb][2] + bsw[cb][2], 0.f);
                float v3 = fmaxf(acc[rb][cb][3] + bsw[cb][3], 0.f);
                unsigned int w0 = cvtpk(v0, v1), w1 = cvtpk(v2, v3);
                int u0 = wc + cb * 16 + lh * 4;
                int sg = (u0 >> 3) ^ (prow & 15);
                unsigned int* dst = (unsigned int*)(X + prow * 256 + sg * 8 + (u0 & 7));
                dst[0] = w0; dst[1] = w1;
            }
        }
        __syncthreads();
    }

    // ---- g4 (unswapped) + masked pair-sum ----
    {
        f32x4 acc[8][4];
        #pragma unroll
        for (int rb = 0; rb < 8; ++rb)
            #pragma unroll
            for (int cb = 0; cb < 4; ++cb) acc[rb][cb] = (f32x4){0.f,0.f,0.f,0.f};
        gemm_k128<false>(w4, X, lr, lh, wc, acc);

        float bias[4];
        #pragma unroll
        for (int cb = 0; cb < 4; ++cb) bias[cb] = b4[wc + cb * 16 + lr];

        float csum[4] = {0.f, 0.f, 0.f, 0.f};
        #pragma unroll
        for (int rb = 0; rb < 8; ++rb) {
            #pragma unroll
            for (int reg = 0; reg < 4; ++reg) {
                int rowloc = rb * 16 + lh * 4 + reg;
                bool valid = (row0 + rowloc) < 625;
                #pragma unroll
                for (int cb = 0; cb < 4; ++cb) {
                    float v = fmaxf(acc[rb][cb][reg] + bias[cb], 0.f);
                    if (valid) csum[cb] += v;
                }
            }
        }
        #pragma unroll
        for (int cb = 0; cb < 4; ++cb) {
            csum[cb] += __shfl_xor(csum[cb], 16);
            csum[cb] += __shfl_xor(csum[cb], 32);
        }
        if (lh == 0) {
            #pragma unroll
            for (int cb = 0; cb < 4; ++cb)
                atomicAdd(&xg[(size_t)b * 256 + wc + cb * 16 + lr], csum[cb]);
        }
    }
}

// ---------- fused f1/f2/f3 ----------
__global__ void fc_fused_kernel(const float* __restrict__ xg,
                                const float* __restrict__ f1w, const float* __restrict__ f1b,
                                const float* __restrict__ f2w, const float* __restrict__ f2b,
                                const float* __restrict__ f3w, const float* __restrict__ f3b,
                                float* __restrict__ out)
{
    __shared__ float xs[256];
    __shared__ float ys[256];
    int b = blockIdx.x, u = threadIdx.x;
    xs[u] = xg[(size_t)b * 256 + u];
    __syncthreads();
    {
        float a = f1b[u];
        const f32x4* wr = (const f32x4*)(f1w + (size_t)u * 256);
        const f32x4* xr = (const f32x4*)xs;
        #pragma unroll 8
        for (int c = 0; c < 64; ++c) {
            f32x4 w = wr[c], x = xr[c];
            a += w[0]*x[0] + w[1]*x[1] + w[2]*x[2] + w[3]*x[3];
        }
        ys[u] = fmaxf(a, 0.f);
    }
    __syncthreads();
    {
        float a = f2b[u];
        const f32x4* wr = (const f32x4*)(f2w + (size_t)u * 256);
        const f32x4* xr = (const f32x4*)ys;
        #pragma unroll 8
        for (int c = 0; c < 64; ++c) {
            f32x4 w = wr[c], x = xr[c];
            a += w[0]*x[0] + w[1]*x[1] + w[2]*x[2] + w[3]*x[3];
        }
        xs[u] = fmaxf(a, 0.f);
    }
    __syncthreads();
    if (u < 10) {
        float a = f3b[u];
        const f32x4* wr = (const f32x4*)(f3w + (size_t)u * 256);
        const f32x4* xr = (const f32x4*)xs;
        for (int c = 0; c < 64; ++c) {
            f32x4 w = wr[c], x = xr[c];
            a += w[0]*x[0] + w[1]*x[1] + w[2]*x[2] + w[3]*x[3];
        }
        out[b * 10 + u] = a;
    }
}

// ---------- launch ----------
extern "C" void kernel_launch(void* const* d_in, const int* in_sizes, int n_in,
                              void* d_out, int out_size, void* d_ws, size_t ws_size,
                              hipStream_t stream)
{
    const float* im  = (const float*)d_in[0];
    const float* q   = (const float*)d_in[1];
    const float* c1w = (const float*)d_in[2];
    const float* c1b = (const float*)d_in[3];
    const float* n1g = (const float*)d_in[4];
    const float* n1b = (const float*)d_in[5];
    const float* c2w = (const float*)d_in[6];
    const float* c2b = (const float*)d_in[7];
    const float* n2g = (const float*)d_in[8];
    const float* n2b = (const float*)d_in[9];
    const float* c3w = (const float*)d_in[10];
    const float* c3b = (const float*)d_in[11];
    const float* n3g = (const float*)d_in[12];
    const float* n3b = (const float*)d_in[13];
    const float* c4w = (const float*)d_in[14];
    const float* c4b = (const float*)d_in[15];
    const float* n4g = (const float*)d_in[16];
    const float* n4b = (const float*)d_in[17];
    const float* g1w = (const float*)d_in[18];
    const float* g1b = (const float*)d_in[19];
    const float* g2w = (const float*)d_in[20];
    const float* g2b = (const float*)d_in[21];
    const float* g3w = (const float*)d_in[22];
    const float* g3b = (const float*)d_in[23];
    const float* g4w = (const float*)d_in[24];
    const float* g4b = (const float*)d_in[25];
    const float* f1w = (const float*)d_in[26];
    const float* f1b = (const float*)d_in[27];
    const float* f2w = (const float*)d_in[28];
    const float* f2b = (const float*)d_in[29];
    const float* f3w = (const float*)d_in[30];
    const float* f3b = (const float*)d_in[31];

    char* ws = (char*)d_ws;
    size_t off = 0;
    auto alloc = [&](size_t bytes) -> void* {
        void* p = ws + off;
        off += (bytes + 255) & ~(size_t)255;
        return p;
    };
    unsigned short* c1o = (unsigned short*)alloc(19660800ull * 2);
    unsigned short* A   = c1o;                       // 3,276,800 u
    unsigned short* Bv  = c1o + 3276800;             // 3,276,800 u
    unsigned short* c3o = c1o + 6553600;             // 1,228,800 u
    unsigned short* Xf  = c1o + 7782400;             //   409,600 u
    unsigned short* c2o = (unsigned short*)alloc(4915200ull * 2);
    unsigned short* W1t = (unsigned short*)alloc(16384ull * 2);
    unsigned short* wg2 = (unsigned short*)alloc(65536ull * 2);
    unsigned short* wg3 = (unsigned short*)alloc(65536ull * 2);
    unsigned short* wg4 = (unsigned short*)alloc(65536ull * 2);
    float* Cq  = (float*)alloc(131072ull * 4);
    float* xg  = (float*)alloc(131072ull * 4);

    conv1_kernel<<<(819200 + 255) / 256, 256, 0, stream>>>(im, c1w, c1b, n1g, n1b, c1o);
    convN_kernel<<<(204800 + 255) / 256, 256, 0, stream>>>(c1o, c2w, c2b, n2g, n2b, c2o, 512, 40, 40, 20, 20);
    convN_kernel<<<(51200  + 255) / 256, 256, 0, stream>>>(c2o, c3w, c3b, n3g, n3b, c3o, 512, 20, 20, 10, 10);
    conv4_kernel<<<(12800  + 255) / 256, 256, 0, stream>>>(c3o, c4w, c4b, n4g, n4b, Xf);

    prep_misc_kernel<<<1856, 256, 0, stream>>>(g1w, g1b, g2w, g3w, g4w, q,
                                               W1t, wg2, wg3, wg4, xg, Cq);

    prep_gemm_kernel<<<200, 512, 0, stream>>>(Xf, W1t, Cq, A, Bv);

    gmlp_kernel<<<512 * 5, 256, 0, stream>>>(A, Bv, wg2, g2b, wg3, g3b, wg4, g4b, xg);

    fc_fused_kernel<<<512, 256, 0, stream>>>(xg, f1w, f1b, f2w, f2b, f3w, f3b, (float*)d_out);
}